// Round 8
// baseline (378.390 us; speedup 1.0000x reference)
//
#include <hip/hip_runtime.h>
#include <hip/hip_bf16.h>

// ---------- complex helpers ----------
__device__ inline float2 cadd(float2 a, float2 b){ return make_float2(a.x+b.x, a.y+b.y); }
__device__ inline float2 csub(float2 a, float2 b){ return make_float2(a.x-b.x, a.y-b.y); }
__device__ inline float2 cmul(float2 a, float2 b){
    return make_float2(fmaf(a.x,b.x,-a.y*b.y), fmaf(a.x,b.y,a.y*b.x));
}

#define NPIX 60516      // 246*246
#define NFFT 288
#define NFFT2 82944     // 288*288
#define XW 152          // padded half-spectrum width (valid x: 0..144)
#define SPLANE (NFFT*XW)
#define CST 312         // per-FFT LDS stride (needs >= 305 for transpose slots; 312 gives clean banking)

// ---------- butterflies ----------
template<bool INV>
__device__ inline void bf4(float2 a0, float2 a1, float2 a2, float2 a3,
                           float2& b0, float2& b1, float2& b2, float2& b3) {
    float2 t0=cadd(a0,a2), t1=csub(a0,a2), t2=cadd(a1,a3), t3=csub(a1,a3);
    b0=cadd(t0,t2); b2=csub(t0,t2);
    if (!INV) { b1=make_float2(t1.x+t3.y, t1.y-t3.x); b3=make_float2(t1.x-t3.y, t1.y+t3.x); }
    else      { b1=make_float2(t1.x-t3.y, t1.y+t3.x); b3=make_float2(t1.x+t3.y, t1.y-t3.x); }
}
template<bool INV>
__device__ inline void bf3(float2 a0, float2 a1, float2 a2,
                           float2& b0, float2& b1, float2& b2) {
    const float d = INV ? 0.8660254037844386f : -0.8660254037844386f;
    float2 tt=cadd(a1,a2), u=csub(a1,a2);
    b0=cadd(a0,tt);
    b1=make_float2(a0.x-0.5f*tt.x - d*u.y, a0.y-0.5f*tt.y + d*u.x);
    b2=make_float2(a0.x-0.5f*tt.x + d*u.y, a0.y-0.5f*tt.y - d*u.x);
}
template<bool INV>
__device__ inline float2 twc(float cc, float ss){ return make_float2(cc, INV ? -ss : ss); }

// ---------- 16-pt FFT in registers (natural in/out), W16 hardcoded ----------
template<bool INV>
__device__ inline void fft16r(float2* u) {
    const float C[10]  = {1.f, 0.9238795325112867f, 0.7071067811865476f, 0.3826834323650898f, 0.f,
                          -0.3826834323650898f, -0.7071067811865476f, -0.9238795325112867f, -1.f, -0.9238795325112867f};
    const float Sn[10] = {0.f, -0.3826834323650898f, -0.7071067811865476f, -0.9238795325112867f, -1.f,
                          -0.9238795325112867f, -0.7071067811865476f, -0.3826834323650898f, 0.f, 0.3826834323650898f};
    float2 v[16];
    #pragma unroll
    for (int p = 0; p < 4; p++) {
        float2 b0,b1,b2,b3;
        bf4<INV>(u[p], u[p+4], u[p+8], u[p+12], b0,b1,b2,b3);
        v[4*p]   = b0;
        v[4*p+1] = cmul(b1, twc<INV>(C[p],   Sn[p]));
        v[4*p+2] = cmul(b2, twc<INV>(C[2*p], Sn[2*p]));
        v[4*p+3] = cmul(b3, twc<INV>(C[3*p], Sn[3*p]));
    }
    #pragma unroll
    for (int q = 0; q < 4; q++) {
        float2 b0,b1,b2,b3;
        bf4<INV>(v[q], v[q+4], v[q+8], v[q+12], b0,b1,b2,b3);
        u[q] = b0; u[q+4] = b1; u[q+8] = b2; u[q+12] = b3;
    }
}

// ---------- 18-pt FFT in registers (natural in/out), stages 2*3*3, W18 hardcoded ----------
template<bool INV>
__device__ inline void fft18r(float2* g) {
    const float C[9]  = {1.f, 0.9396926207859084f, 0.7660444431189780f, 0.5f, 0.1736481776669304f,
                         -0.1736481776669303f, -0.5f, -0.7660444431189779f, -0.9396926207859083f};
    const float Sn[9] = {0.f, -0.3420201433256687f, -0.6427876096865393f, -0.8660254037844386f, -0.9848077530122080f,
                         -0.9848077530122080f, -0.8660254037844387f, -0.6427876096865395f, -0.3420201433256689f};
    float2 h[18];
    #pragma unroll
    for (int p = 0; p < 9; p++) {
        float2 a = g[p], b = g[p+9];
        h[2*p]   = cadd(a,b);
        h[2*p+1] = cmul(csub(a,b), twc<INV>(C[p], Sn[p]));
    }
    float2 e[18];
    #pragma unroll
    for (int p = 0; p < 3; p++) {
        #pragma unroll
        for (int q = 0; q < 2; q++) {
            float2 b0,b1,b2;
            bf3<INV>(h[q+2*p], h[q+2*p+6], h[q+2*p+12], b0,b1,b2);
            e[q+2*(3*p)]   = b0;
            e[q+2*(3*p+1)] = cmul(b1, twc<INV>(C[2*p], Sn[2*p]));
            e[q+2*(3*p+2)] = cmul(b2, twc<INV>(C[4*p], Sn[4*p]));
        }
    }
    #pragma unroll
    for (int q = 0; q < 6; q++) {
        float2 b0,b1,b2;
        bf3<INV>(e[q], e[q+6], e[q+12], b0,b1,b2);
        g[q] = b0; g[q+6] = b1; g[q+12] = b2;
    }
}

// ---------- 288-pt FFT over LDS region base[0..287] (natural order in/out) ----------
// 8 FFTs per 256-thread block: c = t>>5 selects FFT, l = t&31 is the lane within the FFT group.
// One LDS transpose (slots 17*n2+k1, max 304 < CST). Caller syncs after.
template<bool INV>
__device__ inline void fft288_reg(float2* base, int l, const float2* __restrict__ tw) {
    float2 u[16];
    if (l < 18) {
        #pragma unroll
        for (int n1 = 0; n1 < 16; n1++) u[n1] = base[18*n1 + l];
    }
    __syncthreads();
    if (l < 18) {
        fft16r<INV>(u);
        #pragma unroll
        for (int k1 = 0; k1 < 16; k1++) {
            float2 w = tw[l*k1];
            if (INV) w.y = -w.y;
            base[17*l + k1] = cmul(u[k1], w);
        }
    }
    __syncthreads();
    float2 g[18];
    if (l < 16) {
        #pragma unroll
        for (int n2 = 0; n2 < 18; n2++) g[n2] = base[17*n2 + l];
    }
    __syncthreads();
    if (l < 16) {
        fft18r<INV>(g);
        #pragma unroll
        for (int k2 = 0; k2 < 18; k2++) base[16*k2 + l] = g[k2];
    }
}

// ---------- prep: twiddles + zero pooled ----------
__global__ void k_tw(float2* tw, float* pooled) {
    int t = threadIdx.x;
    if (t < NFFT) {
        double ang = -2.0 * 3.14159265358979323846 * (double)t / (double)NFFT;
        tw[t] = make_float2((float)cos(ang), (float)sin(ang));
    }
    for (int i = t; i < 1152; i += 320) pooled[i] = 0.f;
}

// ---------- 1x1 conv 64->16, 4 px/thread float4 ----------
__global__ __launch_bounds__(256) void k_conv1x1_red(const float* __restrict__ x,
        const float* __restrict__ w, const float* __restrict__ bias, float* __restrict__ out) {
    const int NP4 = NPIX/4;
    int idx = blockIdx.x * 256 + threadIdx.x;
    if (idx >= 8 * NP4) return;
    int b = idx / NP4, p4 = idx % NP4;
    const float4* xb = (const float4*)(x + (size_t)b * 64 * NPIX) + p4;
    float4 acc[16];
    #pragma unroll
    for (int co = 0; co < 16; co++) { float bb = bias[co]; acc[co] = make_float4(bb,bb,bb,bb); }
    for (int ci = 0; ci < 64; ci++) {
        float4 v = xb[(size_t)ci * NP4];
        #pragma unroll
        for (int co = 0; co < 16; co++) {
            float wv = w[co*64+ci];
            acc[co].x = fmaf(wv, v.x, acc[co].x);
            acc[co].y = fmaf(wv, v.y, acc[co].y);
            acc[co].z = fmaf(wv, v.z, acc[co].z);
            acc[co].w = fmaf(wv, v.w, acc[co].w);
        }
    }
    float4* ob = (float4*)(out + (size_t)b * 16 * NPIX) + p4;
    #pragma unroll
    for (int co = 0; co < 16; co++) ob[(size_t)co*NP4] = acc[co];
}

// ---------- 3x3 valid conv 16->16, 4 px/thread, scalar weights ----------
template<int HIN, bool LEAKY>
__global__ __launch_bounds__(256) void k_conv3x3(const float* __restrict__ in,
        const float* __restrict__ w, const float* __restrict__ bias, float* __restrict__ out) {
    const int HOUT = HIN - 2;
    const int GX = (HOUT + 3) / 4;
    int idx = blockIdx.x * 256 + threadIdx.x;
    if (idx >= 8 * HOUT * GX) return;
    int b  = idx / (HOUT * GX);
    int r  = idx % (HOUT * GX);
    int oy = r / GX;
    int ox0 = (r % GX) * 4;

    float acc[16][4];
    #pragma unroll
    for (int co = 0; co < 16; co++) {
        float bb = bias[co];
        #pragma unroll
        for (int px = 0; px < 4; px++) acc[co][px] = bb;
    }
    const float* ib = in + (size_t)b * 16 * HIN * HIN + (size_t)oy * HIN;
    for (int ci = 0; ci < 16; ci++) {
        const float* ic = ib + (size_t)ci * HIN * HIN;
        #pragma unroll
        for (int ky = 0; ky < 3; ky++) {
            float in6[6];
            #pragma unroll
            for (int j = 0; j < 6; j++) {
                int xx = ox0 + j;
                if (HOUT % 4 != 0) { if (xx > HIN - 1) xx = HIN - 1; }
                in6[j] = ic[ky * HIN + xx];
            }
            #pragma unroll
            for (int kx = 0; kx < 3; kx++) {
                #pragma unroll
                for (int co = 0; co < 16; co++) {
                    float wv = w[co*144 + ci*9 + ky*3 + kx];
                    #pragma unroll
                    for (int px = 0; px < 4; px++)
                        acc[co][px] = fmaf(wv, in6[px + kx], acc[co][px]);
                }
            }
        }
    }
    float* ob = out + (size_t)b * 16 * HOUT * HOUT + (size_t)oy * HOUT + ox0;
    #pragma unroll
    for (int co = 0; co < 16; co++) {
        #pragma unroll
        for (int px = 0; px < 4; px++) {
            if (HOUT % 4 == 0 || ox0 + px < HOUT) {
                float v = acc[co][px];
                if (LEAKY) v = (v >= 0.f) ? v : 0.1f * v;
                ob[(size_t)co * HOUT * HOUT + px] = v;
            }
        }
    }
}

// ---------- 3x3 conv (242->240) fused with adaptive pool -> pooled (raw sums) ----------
__global__ __launch_bounds__(256) void k_conv3x3_pool(const float* __restrict__ in,
        const float* __restrict__ w, const float* __restrict__ bias, float* __restrict__ pooled) {
    const int HIN = 242, GX = 60;
    __shared__ float cs[144];
    int t = threadIdx.x;
    int b = blockIdx.x / 57;
    int r = (blockIdx.x % 57) * 256 + t;
    bool valid = r < 14400;
    float partial[16];
    int cell = 0;
    if (valid) {
        int oy = r / GX, ox0 = (r % GX) * 4;
        cell = (oy / 80) * 3 + (ox0 / 80);
        float acc[16][4];
        #pragma unroll
        for (int co = 0; co < 16; co++) {
            float bb = bias[co];
            #pragma unroll
            for (int px = 0; px < 4; px++) acc[co][px] = bb;
        }
        const float* ib = in + (size_t)b * 16 * HIN * HIN + (size_t)oy * HIN;
        for (int ci = 0; ci < 16; ci++) {
            const float* ic = ib + (size_t)ci * HIN * HIN;
            #pragma unroll
            for (int ky = 0; ky < 3; ky++) {
                float in6[6];
                #pragma unroll
                for (int j = 0; j < 6; j++) in6[j] = ic[ky * HIN + ox0 + j];
                #pragma unroll
                for (int kx = 0; kx < 3; kx++) {
                    #pragma unroll
                    for (int co = 0; co < 16; co++) {
                        float wv = w[co*144 + ci*9 + ky*3 + kx];
                        #pragma unroll
                        for (int px = 0; px < 4; px++)
                            acc[co][px] = fmaf(wv, in6[px + kx], acc[co][px]);
                    }
                }
            }
        }
        #pragma unroll
        for (int co = 0; co < 16; co++)
            partial[co] = (acc[co][0] + acc[co][1]) + (acc[co][2] + acc[co][3]);
    }
    if (t < 144) cs[t] = 0.f;
    __syncthreads();
    if (valid) {
        #pragma unroll
        for (int co = 0; co < 16; co++) atomicAdd(&cs[co*9 + cell], partial[co]);
    }
    __syncthreads();
    if (t < 144) atomicAdd(&pooled[b*144 + t], cs[t]);
}

// ---------- kernel_P: 1x1 conv (16->16) + exp + spatial-mean subtraction ----------
__global__ void k_kernelP(const float* __restrict__ pooled, const float* __restrict__ w,
                          const float* __restrict__ bias, float* __restrict__ out) {
    int b = blockIdx.x / 16, co = blockIdx.x % 16;
    __shared__ float vals[9];
    int t = threadIdx.x;
    if (t < 9) {
        float a = 0.f;
        for (int ci = 0; ci < 16; ci++) a += pooled[(b*16+ci)*9 + t] * w[co*16+ci];
        vals[t] = expf(bias[co] + a * (1.f/6400.f));
    }
    __syncthreads();
    if (t < 9) {
        float m = 0.f;
        #pragma unroll
        for (int i = 0; i < 9; i++) m += vals[i];
        m *= (1.f/9.f);
        out[(b*16+co)*9 + t] = vals[t] - m;
    }
}

// ---------- psf builder for K, TRANSPOSED: KfT[b][u][v] = psf[b][v][u] ----------
__global__ __launch_bounds__(256) void k_psfKT(const float* __restrict__ ker, float2* __restrict__ KfT) {
    int idx = blockIdx.x*256 + threadIdx.x;
    if (idx >= 8*NFFT2) return;
    int pos = idx % NFFT2, b = idx / NFFT2;
    int u = pos / NFFT, v = pos % NFFT;
    int ry = (v < 11) ? v+10 : ((v >= 278) ? v-278 : -1);
    int rx = (u < 11) ? u+10 : ((u >= 278) ? u-278 : -1);
    float val = (ry >= 0 && rx >= 0) ? ker[b*441 + ry*21 + rx] : 0.f;
    KfT[idx] = make_float2(val, 0.f);
}

// ---------- K pipeline: row FFT (8 rows/block, in place) ----------
__global__ __launch_bounds__(256) void k_fftK_rows(float2* __restrict__ M, const float2* __restrict__ tw) {
    __shared__ float2 L[8*CST];
    int t = threadIdx.x, c = t>>5, l = t&31;
    float2* mb = M + (size_t)blockIdx.x * 8 * NFFT;
    for (int idx = t; idx < 2304; idx += 256) L[(idx/288)*CST + idx%288] = mb[idx];
    __syncthreads();
    fft288_reg<false>(L + c*CST, l, tw);
    __syncthreads();
    for (int idx = t; idx < 2304; idx += 256) mb[idx] = L[(idx/288)*CST + idx%288];
}

// ---------- K pipeline: col FFT (8 cols/block, in place) ----------
__global__ __launch_bounds__(256) void k_fftK_cols(float2* __restrict__ M, const float2* __restrict__ tw) {
    __shared__ float2 L[8*CST];
    int t = threadIdx.x, c = t>>5, l = t&31;
    int ch = blockIdx.x / 36, grp = blockIdx.x % 36;
    float2* mb = M + (size_t)ch * NFFT2 + grp*8;
    for (int idx = t; idx < 2304; idx += 256) {
        int f = idx & 7, yy = idx >> 3;
        L[f*CST + yy] = mb[(size_t)yy * NFFT + f];
    }
    __syncthreads();
    fft288_reg<false>(L + c*CST, l, tw);
    __syncthreads();
    for (int idx = t; idx < 2304; idx += 256) {
        int f = idx & 7, yy = idx >> 3;
        mb[(size_t)yy * NFFT + f] = L[f*CST + yy];
    }
}

// ---------- forward row FFT + edge-pad + per-row real unpack -> half spectra S ----------
__global__ __launch_bounds__(256) void k_fft_rows_pad_half(const float* __restrict__ cls,
        float2* __restrict__ S, const float2* __restrict__ tw) {
    __shared__ float2 L[8*CST];
    int t = threadIdx.x, c = t>>5, l = t&31;
    int pc = blockIdx.x / 36;            // packed channel 0..63
    int y0 = (blockIdx.x % 36) * 8;
    const float* c0base = cls + (size_t)(2*pc)*NPIX;
    for (int idx = t; idx < 2304; idx += 256) {
        int f = idx / 288, j = idx % 288;
        int iy = min(max(y0 + f - 21, 0), 245);
        int ix = min(max(j - 21, 0), 245);
        const float* p = c0base + iy*246 + ix;
        L[f*CST + j] = make_float2(p[0], p[NPIX]);
    }
    __syncthreads();
    fft288_reg<false>(L + c*CST, l, tw);
    __syncthreads();
    int chA = (pc >> 3)*16 + (pc & 7)*2;
    float2* sA = S + (size_t)chA * SPLANE;
    for (int idx = t; idx < 8*XW; idx += 256) {
        int f = idx / XW, x = idx % XW;
        int y = y0 + f;
        float2 zk = L[f*CST + x];
        float2 zm = L[f*CST + ((288 - x) % 288)];
        float2 Av = make_float2(0.5f*(zk.x+zm.x),  0.5f*(zk.y-zm.y));
        float2 Bv = make_float2(0.5f*(zk.y+zm.y), -0.5f*(zk.x-zm.x));
        sA[(size_t)y*XW + x] = Av;
        sA[SPLANE + (size_t)y*XW + x] = Bv;
    }
}

// ---------- FUSED: fwd col FFT + pointwise Wiener (analytic P) + inv col FFT ----------
__global__ __launch_bounds__(256) void k_fft_cols_filter(float2* __restrict__ S,
        const float2* __restrict__ KfT, const float* __restrict__ kP, const float2* __restrict__ tw) {
    __shared__ float2 L[8*CST];
    int t = threadIdx.x, c = t>>5, l = t&31;
    int g = blockIdx.x >> 7;          // 19 col-groups (g-major grid: K slice L2-resident)
    int ch = blockIdx.x & 127;
    int b = ch >> 4;
    float2* sc = S + (size_t)ch * SPLANE + g*8;
    for (int idx = t; idx < 2304; idx += 256) {
        int f = idx & 7, y = idx >> 3;
        L[f*CST + y] = sc[(size_t)y * XW + f];
    }
    __syncthreads();
    fft288_reg<false>(L + c*CST, l, tw);
    __syncthreads();
    // pointwise Wiener in LDS
    {
        const float* p9 = kP + ch*9;
        float pv[9];
        #pragma unroll
        for (int i = 0; i < 9; i++) pv[i] = p9[i];
        for (int idx = t; idx < 2304; idx += 256) {
            int f = idx / 288, ky = idx % 288;
            int x = g*8 + f;
            float2 wx = tw[x], wy = tw[ky];
            float2 K = KfT[(size_t)b*NFFT2 + (size_t)x*NFFT + ky];
            float2 R0 = make_float2(pv[1] + (pv[0]+pv[2])*wx.x, (pv[2]-pv[0])*wx.y);
            float2 R1 = make_float2(pv[4] + (pv[3]+pv[5])*wx.x, (pv[5]-pv[3])*wx.y);
            float2 R2 = make_float2(pv[7] + (pv[6]+pv[8])*wx.x, (pv[8]-pv[6])*wx.y);
            float2 P;
            P.x = R1.x + wy.x*(R0.x+R2.x) - wy.y*(R2.y-R0.y);
            P.y = R1.y + wy.x*(R0.y+R2.y) + wy.y*(R2.x-R0.x);
            float kk = K.x*K.x + K.y*K.y;
            float rcp = 1.0f / (kk + P.x*P.x + P.y*P.y);
            float2 H = make_float2(K.x*rcp, -K.y*rcp);
            L[f*CST + ky] = cmul(H, L[f*CST + ky]);
        }
    }
    __syncthreads();
    fft288_reg<true>(L + c*CST, l, tw);
    __syncthreads();
    // write back only rows needed by the crop [21,267)
    for (int idx = t; idx < 8*246; idx += 256) {
        int f = idx & 7, rr = idx >> 3;
        sc[(size_t)(rr + 21) * XW + f] = L[f*CST + rr + 21];
    }
}

// ---------- FUSED: repack + inverse row FFT + crop + 1x1 conv 16->64 (2px/thread, float2 stores) ----------
__global__ __launch_bounds__(256) void k_ifft_rows_conv(const float2* __restrict__ S,
        const float* __restrict__ w_exp, const float* __restrict__ b_exp,
        float* __restrict__ out, const float2* __restrict__ tw) {
    __shared__ float2 L[8*CST];
    int t = threadIdx.x, c = t>>5, l = t&31;
    int b = blockIdx.x / 246;
    int rseq = blockIdx.x % 246;
    int y = rseq + 21;
    const float2* sbase = S + (size_t)(b*16) * SPLANE + (size_t)y * XW;
    for (int idx = t; idx < 2304; idx += 256) {
        int h = idx & 7, j = idx >> 3;
        const float2* sA = sbase + (size_t)(2*h) * SPLANE;
        float2 z;
        if (j <= 144) {
            float2 a = sA[j], bb = sA[SPLANE + j];
            z = make_float2(a.x - bb.y, a.y + bb.x);
        } else {
            int m = 288 - j;
            float2 a = sA[m], bb = sA[SPLANE + m];
            z = make_float2(a.x + bb.y, bb.x - a.y);
        }
        L[h*CST + j] = z;
    }
    __syncthreads();
    fft288_reg<true>(L + c*CST, l, tw);
    __syncthreads();
    // conv 1x1 16->64: threads split {x-pair} x {co half}
    int tt = t & 127;
    int co0 = (t >> 7) * 32;
    if (tt < 123) {
        int x0 = 2*tt;
        const float sc = 1.0f / 82944.0f;
        float v0[16], v1[16];
        #pragma unroll
        for (int h = 0; h < 8; h++) {
            float2 z0 = L[h*CST + x0 + 21];
            float2 z1 = L[h*CST + x0 + 22];
            v0[2*h] = z0.x*sc; v0[2*h+1] = z0.y*sc;
            v1[2*h] = z1.x*sc; v1[2*h+1] = z1.y*sc;
        }
        float* ob = out + (size_t)b * 64 * NPIX + (size_t)rseq * 246 + x0;
        #pragma unroll
        for (int co = 0; co < 32; co++) {
            const float* wr = w_exp + (co0 + co)*16;
            float a0 = b_exp[co0 + co], a1 = a0;
            #pragma unroll
            for (int ci = 0; ci < 16; ci++) {
                a0 = fmaf(wr[ci], v0[ci], a0);
                a1 = fmaf(wr[ci], v1[ci], a1);
            }
            *(float2*)(ob + (size_t)(co0 + co) * NPIX) = make_float2(a0, a1);
        }
    }
}

extern "C" void kernel_launch(void* const* d_in, const int* in_sizes, int n_in,
                              void* d_out, int out_size, void* d_ws, size_t ws_size,
                              hipStream_t stream) {
    const float* x     = (const float*)d_in[0];
    const float* ker   = (const float*)d_in[1];
    const float* w_red = (const float*)d_in[2];
    const float* b_red = (const float*)d_in[3];
    const float* w_g1  = (const float*)d_in[4];
    const float* b_g1  = (const float*)d_in[5];
    const float* w_g2  = (const float*)d_in[6];
    const float* b_g2  = (const float*)d_in[7];
    const float* w_g3  = (const float*)d_in[8];
    const float* b_g3  = (const float*)d_in[9];
    const float* w_g4  = (const float*)d_in[10];
    const float* b_g4  = (const float*)d_in[11];
    const float* w_exp = (const float*)d_in[12];
    const float* b_exp = (const float*)d_in[13];
    float* out = (float*)d_out;

    char* ws = (char*)d_ws;
    size_t off = 0;
    auto alloc = [&](size_t bytes) -> char* {
        char* p = ws + off; off += (bytes + 255) & ~(size_t)255; return p;
    };
    float*  cls    = (float*) alloc(7746048ull * 4);              // (8,16,246,246)
    float2* S      = (float2*)alloc((size_t)128 * SPLANE * 8);    // half spectra (128,288,152)
    float*  hb     = (float*) alloc(7495712ull * 4);              // (8,16,242,242) dedicated
    float2* KfT    = (float2*)alloc((size_t)8 * NFFT2 * 8);       // K spectrum transposed
    float*  pooled = (float*) alloc(1152 * 4);
    float*  kP     = (float*) alloc(1152 * 4);
    float2* tw     = (float2*)alloc(288 * 8);
    // ha aliases S (needs 7,620,608 floats <= 11,206,656 float2 of S; dead before S written)
    float*  ha     = (float*)S;

    k_tw<<<1, 320, 0, stream>>>(tw, pooled);
    k_conv1x1_red<<<473, 256, 0, stream>>>(x, w_red, b_red, cls);
    k_conv3x3<246, true ><<<466, 256, 0, stream>>>(cls, w_g1, b_g1, ha);
    k_conv3x3<244, true ><<<462, 256, 0, stream>>>(ha,  w_g2, b_g2, hb);
    k_conv3x3_pool<<<456, 256, 0, stream>>>(hb, w_g3, b_g3, pooled);
    k_kernelP<<<128, 64, 0, stream>>>(pooled, w_g4, b_g4, kP);

    // KfT = fft2(psf(kernel)^T)
    k_psfKT<<<2592, 256, 0, stream>>>(ker, KfT);
    k_fftK_rows<<<288, 256, 0, stream>>>(KfT, tw);
    k_fftK_cols<<<288, 256, 0, stream>>>(KfT, tw);

    // S = per-row-unpacked half spectra of edge-padded cls (packed row FFT)
    // ROUND-7 BUG FIX: grid must be 64 packed-channels x 36 row-groups = 2304 (was 576)
    k_fft_rows_pad_half<<<2304, 256, 0, stream>>>(cls, S, tw);

    // fwd col FFT + pointwise Wiener + inv col FFT
    k_fft_cols_filter<<<19*128, 256, 0, stream>>>(S, KfT, kP, tw);

    // repack + inverse row FFT + crop + final 1x1 conv
    k_ifft_rows_conv<<<1968, 256, 0, stream>>>(S, w_exp, b_exp, out, tw);
}

// Round 10
// 341.672 us; speedup vs baseline: 1.1075x; 1.1075x over previous
//
#include <hip/hip_runtime.h>
#include <hip/hip_bf16.h>

// ---------- complex helpers ----------
__device__ inline float2 cadd(float2 a, float2 b){ return make_float2(a.x+b.x, a.y+b.y); }
__device__ inline float2 csub(float2 a, float2 b){ return make_float2(a.x-b.x, a.y-b.y); }
__device__ inline float2 cmul(float2 a, float2 b){
    return make_float2(fmaf(a.x,b.x,-a.y*b.y), fmaf(a.x,b.y,a.y*b.x));
}

#define NPIX 60516      // 246*246
#define NFFT 288
#define NFFT2 82944     // 288*288
#define XW 152          // padded half-spectrum width (valid x: 0..144)
#define SPLANE (NFFT*XW)

// LDS index for the 8-col layout: stride 8 + 1 pad float2 per 4 rows (38 KB/buffer-pair -> 4 blocks/CU)
__device__ inline int lidx(int i, int c){ return i*8 + (i>>2) + c; }
#define LDSN 2376

// ---------- butterflies ----------
template<bool INV>
__device__ inline void bf4(float2 a0, float2 a1, float2 a2, float2 a3,
                           float2& b0, float2& b1, float2& b2, float2& b3) {
    float2 t0=cadd(a0,a2), t1=csub(a0,a2), t2=cadd(a1,a3), t3=csub(a1,a3);
    b0=cadd(t0,t2); b2=csub(t0,t2);
    if (!INV) { b1=make_float2(t1.x+t3.y, t1.y-t3.x); b3=make_float2(t1.x-t3.y, t1.y+t3.x); }
    else      { b1=make_float2(t1.x-t3.y, t1.y+t3.x); b3=make_float2(t1.x+t3.y, t1.y-t3.x); }
}
template<bool INV>
__device__ inline void bf3(float2 a0, float2 a1, float2 a2,
                           float2& b0, float2& b1, float2& b2) {
    const float d = INV ? 0.8660254037844386f : -0.8660254037844386f;
    float2 tt=cadd(a1,a2), u=csub(a1,a2);
    b0=cadd(a0,tt);
    b1=make_float2(a0.x-0.5f*tt.x - d*u.y, a0.y-0.5f*tt.y + d*u.x);
    b2=make_float2(a0.x-0.5f*tt.x + d*u.y, a0.y-0.5f*tt.y - d*u.x);
}

// ---------- 288-pt Stockham core, contiguous layout (one wave per row) ----------
template<bool INV>
__device__ inline void fft288_row(float2*& X, float2*& Y, int lane, const float2* __restrict__ tw) {
    auto TW = [&](int k) { float2 v = tw[k]; if (INV) v.y = -v.y; return v; };
    for (int p = lane; p < 72; p += 64) {
        float2 b0,b1,b2,b3;
        bf4<INV>(X[p], X[p+72], X[p+144], X[p+216], b0,b1,b2,b3);
        Y[4*p]=b0; Y[4*p+1]=cmul(b1,TW(p)); Y[4*p+2]=cmul(b2,TW(2*p)); Y[4*p+3]=cmul(b3,TW(3*p));
    }
    __syncthreads(); { float2* t=X; X=Y; Y=t; }
    for (int it = lane; it < 72; it += 64) {
        int p = it>>2, q = it&3, i0 = q+4*p;
        float2 b0,b1,b2,b3;
        bf4<INV>(X[i0], X[i0+72], X[i0+144], X[i0+216], b0,b1,b2,b3);
        int o = q+16*p;
        Y[o]=b0; Y[o+4]=cmul(b1,TW(4*p)); Y[o+8]=cmul(b2,TW(8*p)); Y[o+12]=cmul(b3,TW(12*p));
    }
    __syncthreads(); { float2* t=X; X=Y; Y=t; }
    for (int it = lane; it < 144; it += 64) {
        int p = it>>4, q = it&15, i0 = q+16*p;
        float2 a0=X[i0], a1=X[i0+144];
        int o = q+32*p;
        Y[o]=cadd(a0,a1); Y[o+16]=cmul(csub(a0,a1),TW(16*p));
    }
    __syncthreads(); { float2* t=X; X=Y; Y=t; }
    for (int it = lane; it < 96; it += 64) {
        int p = it>>5, q = it&31, i0 = q+32*p;
        float2 b0,b1,b2;
        bf3<INV>(X[i0], X[i0+96], X[i0+192], b0,b1,b2);
        int o = q+96*p;
        Y[o]=b0; Y[o+32]=cmul(b1,TW(32*p)); Y[o+64]=cmul(b2,TW(64*p));
    }
    __syncthreads(); { float2* t=X; X=Y; Y=t; }
    for (int q = lane; q < 96; q += 64) {
        float2 b0,b1,b2;
        bf3<INV>(X[q], X[q+96], X[q+192], b0,b1,b2);
        Y[q]=b0; Y[q+96]=b1; Y[q+192]=b2;
    }
    __syncthreads(); { float2* t=X; X=Y; Y=t; }
}

// ---------- 288-pt Stockham core, lidx layout (8 lanes share, 32 row-slots) ----------
template<bool INV>
__device__ inline void fft288_s9(float2*& X, float2*& Y, int w, int c, const float2* __restrict__ tw) {
    auto TW = [&](int k) { float2 v = tw[k]; if (INV) v.y = -v.y; return v; };
    for (int p = w; p < 72; p += 32) {
        float2 b0,b1,b2,b3;
        bf4<INV>(X[lidx(p,c)], X[lidx(p+72,c)], X[lidx(p+144,c)], X[lidx(p+216,c)], b0,b1,b2,b3);
        Y[lidx(4*p,c)]=b0; Y[lidx(4*p+1,c)]=cmul(b1,TW(p));
        Y[lidx(4*p+2,c)]=cmul(b2,TW(2*p)); Y[lidx(4*p+3,c)]=cmul(b3,TW(3*p));
    }
    __syncthreads(); { float2* t=X; X=Y; Y=t; }
    for (int it = w; it < 72; it += 32) {
        int p = it>>2, q = it&3, i0 = q+4*p;
        float2 b0,b1,b2,b3;
        bf4<INV>(X[lidx(i0,c)], X[lidx(i0+72,c)], X[lidx(i0+144,c)], X[lidx(i0+216,c)], b0,b1,b2,b3);
        int o = q+16*p;
        Y[lidx(o,c)]=b0; Y[lidx(o+4,c)]=cmul(b1,TW(4*p));
        Y[lidx(o+8,c)]=cmul(b2,TW(8*p)); Y[lidx(o+12,c)]=cmul(b3,TW(12*p));
    }
    __syncthreads(); { float2* t=X; X=Y; Y=t; }
    for (int it = w; it < 144; it += 32) {
        int p = it>>4, q = it&15, i0 = q+16*p;
        float2 a0=X[lidx(i0,c)], a1=X[lidx(i0+144,c)];
        int o = q+32*p;
        Y[lidx(o,c)]=cadd(a0,a1); Y[lidx(o+16,c)]=cmul(csub(a0,a1),TW(16*p));
    }
    __syncthreads(); { float2* t=X; X=Y; Y=t; }
    for (int it = w; it < 96; it += 32) {
        int p = it>>5, q = it&31, i0 = q+32*p;
        float2 b0,b1,b2;
        bf3<INV>(X[lidx(i0,c)], X[lidx(i0+96,c)], X[lidx(i0+192,c)], b0,b1,b2);
        int o = q+96*p;
        Y[lidx(o,c)]=b0; Y[lidx(o+32,c)]=cmul(b1,TW(32*p)); Y[lidx(o+64,c)]=cmul(b2,TW(64*p));
    }
    __syncthreads(); { float2* t=X; X=Y; Y=t; }
    for (int q = w; q < 96; q += 32) {
        float2 b0,b1,b2;
        bf3<INV>(X[lidx(q,c)], X[lidx(q+96,c)], X[lidx(q+192,c)], b0,b1,b2);
        Y[lidx(q,c)]=b0; Y[lidx(q+96,c)]=b1; Y[lidx(q+192,c)]=b2;
    }
    __syncthreads(); { float2* t=X; X=Y; Y=t; }
}

// ---------- prep: twiddles + zero pooled ----------
__global__ void k_tw(float2* tw, float* pooled) {
    int t = threadIdx.x;
    if (t < NFFT) {
        double ang = -2.0 * 3.14159265358979323846 * (double)t / (double)NFFT;
        tw[t] = make_float2((float)cos(ang), (float)sin(ang));
    }
    for (int i = t; i < 1152; i += 320) pooled[i] = 0.f;
}

// ---------- 1x1 conv 64->16, 4 px/thread float4 (r8-validated) ----------
__global__ __launch_bounds__(256) void k_conv1x1_red(const float* __restrict__ x,
        const float* __restrict__ w, const float* __restrict__ bias, float* __restrict__ out) {
    const int NP4 = NPIX/4;
    int idx = blockIdx.x * 256 + threadIdx.x;
    if (idx >= 8 * NP4) return;
    int b = idx / NP4, p4 = idx % NP4;
    const float4* xb = (const float4*)(x + (size_t)b * 64 * NPIX) + p4;
    float4 acc[16];
    #pragma unroll
    for (int co = 0; co < 16; co++) { float bb = bias[co]; acc[co] = make_float4(bb,bb,bb,bb); }
    for (int ci = 0; ci < 64; ci++) {
        float4 v = xb[(size_t)ci * NP4];
        #pragma unroll
        for (int co = 0; co < 16; co++) {
            float wv = w[co*64+ci];
            acc[co].x = fmaf(wv, v.x, acc[co].x);
            acc[co].y = fmaf(wv, v.y, acc[co].y);
            acc[co].z = fmaf(wv, v.z, acc[co].z);
            acc[co].w = fmaf(wv, v.w, acc[co].w);
        }
    }
    float4* ob = (float4*)(out + (size_t)b * 16 * NPIX) + p4;
    #pragma unroll
    for (int co = 0; co < 16; co++) ob[(size_t)co*NP4] = acc[co];
}

// ---------- 3x3 valid conv 16->16, 4 px/thread, scalar weights ----------
template<int HIN, bool LEAKY>
__global__ __launch_bounds__(256) void k_conv3x3(const float* __restrict__ in,
        const float* __restrict__ w, const float* __restrict__ bias, float* __restrict__ out) {
    const int HOUT = HIN - 2;
    const int GX = (HOUT + 3) / 4;
    int idx = blockIdx.x * 256 + threadIdx.x;
    if (idx >= 8 * HOUT * GX) return;
    int b  = idx / (HOUT * GX);
    int r  = idx % (HOUT * GX);
    int oy = r / GX;
    int ox0 = (r % GX) * 4;

    float acc[16][4];
    #pragma unroll
    for (int co = 0; co < 16; co++) {
        float bb = bias[co];
        #pragma unroll
        for (int px = 0; px < 4; px++) acc[co][px] = bb;
    }
    const float* ib = in + (size_t)b * 16 * HIN * HIN + (size_t)oy * HIN;
    for (int ci = 0; ci < 16; ci++) {
        const float* ic = ib + (size_t)ci * HIN * HIN;
        #pragma unroll
        for (int ky = 0; ky < 3; ky++) {
            float in6[6];
            #pragma unroll
            for (int j = 0; j < 6; j++) {
                int xx = ox0 + j;
                if (HOUT % 4 != 0) { if (xx > HIN - 1) xx = HIN - 1; }
                in6[j] = ic[ky * HIN + xx];
            }
            #pragma unroll
            for (int kx = 0; kx < 3; kx++) {
                #pragma unroll
                for (int co = 0; co < 16; co++) {
                    float wv = w[co*144 + ci*9 + ky*3 + kx];
                    #pragma unroll
                    for (int px = 0; px < 4; px++)
                        acc[co][px] = fmaf(wv, in6[px + kx], acc[co][px]);
                }
            }
        }
    }
    float* ob = out + (size_t)b * 16 * HOUT * HOUT + (size_t)oy * HOUT + ox0;
    #pragma unroll
    for (int co = 0; co < 16; co++) {
        #pragma unroll
        for (int px = 0; px < 4; px++) {
            if (HOUT % 4 == 0 || ox0 + px < HOUT) {
                float v = acc[co][px];
                if (LEAKY) v = (v >= 0.f) ? v : 0.1f * v;
                ob[(size_t)co * HOUT * HOUT + px] = v;
            }
        }
    }
}

// ---------- 3x3 conv (242->240) fused with adaptive pool -> pooled (raw sums) ----------
__global__ __launch_bounds__(256) void k_conv3x3_pool(const float* __restrict__ in,
        const float* __restrict__ w, const float* __restrict__ bias, float* __restrict__ pooled) {
    const int HIN = 242, GX = 60;
    __shared__ float cs[144];
    int t = threadIdx.x;
    int b = blockIdx.x / 57;
    int r = (blockIdx.x % 57) * 256 + t;
    bool valid = r < 14400;
    float partial[16];
    int cell = 0;
    if (valid) {
        int oy = r / GX, ox0 = (r % GX) * 4;
        cell = (oy / 80) * 3 + (ox0 / 80);
        float acc[16][4];
        #pragma unroll
        for (int co = 0; co < 16; co++) {
            float bb = bias[co];
            #pragma unroll
            for (int px = 0; px < 4; px++) acc[co][px] = bb;
        }
        const float* ib = in + (size_t)b * 16 * HIN * HIN + (size_t)oy * HIN;
        for (int ci = 0; ci < 16; ci++) {
            const float* ic = ib + (size_t)ci * HIN * HIN;
            #pragma unroll
            for (int ky = 0; ky < 3; ky++) {
                float in6[6];
                #pragma unroll
                for (int j = 0; j < 6; j++) in6[j] = ic[ky * HIN + ox0 + j];
                #pragma unroll
                for (int kx = 0; kx < 3; kx++) {
                    #pragma unroll
                    for (int co = 0; co < 16; co++) {
                        float wv = w[co*144 + ci*9 + ky*3 + kx];
                        #pragma unroll
                        for (int px = 0; px < 4; px++)
                            acc[co][px] = fmaf(wv, in6[px + kx], acc[co][px]);
                    }
                }
            }
        }
        #pragma unroll
        for (int co = 0; co < 16; co++)
            partial[co] = (acc[co][0] + acc[co][1]) + (acc[co][2] + acc[co][3]);
    }
    if (t < 144) cs[t] = 0.f;
    __syncthreads();
    if (valid) {
        #pragma unroll
        for (int co = 0; co < 16; co++) atomicAdd(&cs[co*9 + cell], partial[co]);
    }
    __syncthreads();
    if (t < 144) atomicAdd(&pooled[b*144 + t], cs[t]);
}

// ---------- kernel_P: 1x1 conv (16->16) + exp + spatial-mean subtraction ----------
__global__ void k_kernelP(const float* __restrict__ pooled, const float* __restrict__ w,
                          const float* __restrict__ bias, float* __restrict__ out) {
    int b = blockIdx.x / 16, co = blockIdx.x % 16;
    __shared__ float vals[9];
    int t = threadIdx.x;
    if (t < 9) {
        float a = 0.f;
        for (int ci = 0; ci < 16; ci++) a += pooled[(b*16+ci)*9 + t] * w[co*16+ci];
        vals[t] = expf(bias[co] + a * (1.f/6400.f));
    }
    __syncthreads();
    if (t < 9) {
        float m = 0.f;
        #pragma unroll
        for (int i = 0; i < 9; i++) m += vals[i];
        m *= (1.f/9.f);
        out[(b*16+co)*9 + t] = vals[t] - m;
    }
}

// ---------- psf builder for K, TRANSPOSED: KfT[b][u][v] = psf[b][v][u] ----------
__global__ __launch_bounds__(256) void k_psfKT(const float* __restrict__ ker, float2* __restrict__ KfT) {
    int idx = blockIdx.x*256 + threadIdx.x;
    if (idx >= 8*NFFT2) return;
    int pos = idx % NFFT2, b = idx / NFFT2;
    int u = pos / NFFT, v = pos % NFFT;
    int ry = (v < 11) ? v+10 : ((v >= 278) ? v-278 : -1);
    int rx = (u < 11) ? u+10 : ((u >= 278) ? u-278 : -1);
    float val = (ry >= 0 && rx >= 0) ? ker[b*441 + ry*21 + rx] : 0.f;
    KfT[idx] = make_float2(val, 0.f);
}

// ---------- plain row FFT (for KfT) ----------
template<bool INV>
__global__ __launch_bounds__(256) void k_fft_rows(float2* __restrict__ M, const float2* __restrict__ tw) {
    __shared__ float2 A[4][NFFT];
    __shared__ float2 B[4][NFFT];
    int t = threadIdx.x, w = t >> 6, lane = t & 63;
    size_t row = (size_t)blockIdx.x*4 + w;
    float2* X = A[w]; float2* Y = B[w];
    float2* s = M + row*NFFT;
    for (int j = lane; j < NFFT; j += 64) X[j] = s[j];
    __syncthreads();
    fft288_row<INV>(X, Y, lane, tw);
    for (int j = lane; j < NFFT; j += 64) s[j] = X[j];
}

// ---------- plain col FFT (for KfT) ----------
template<bool INV>
__global__ __launch_bounds__(256) void k_fft_cols(float2* __restrict__ M, const float2* __restrict__ tw) {
    __shared__ float2 Abuf[LDSN];
    __shared__ float2 Bbuf[LDSN];
    int t = threadIdx.x, c = t & 7, w = t >> 3;
    int ch = blockIdx.x / 36, cg = blockIdx.x % 36;
    float2* base = M + (size_t)ch * NFFT2 + cg*8 + c;
    float2* X = Abuf; float2* Y = Bbuf;
    for (int r = w; r < NFFT; r += 32) X[lidx(r,c)] = base[(size_t)r * NFFT];
    __syncthreads();
    fft288_s9<INV>(X, Y, w, c, tw);
    for (int r = w; r < NFFT; r += 32) base[(size_t)r * NFFT] = X[lidx(r,c)];
}

// ---------- forward row FFT + edge-pad + per-row real unpack -> half spectra S ----------
__global__ __launch_bounds__(256) void k_fft_rows_pad_half(const float* __restrict__ cls,
        float2* __restrict__ S, const float2* __restrict__ tw) {
    __shared__ float2 A[4][NFFT];
    __shared__ float2 B[4][NFFT];
    int t = threadIdx.x, w = t >> 6, lane = t & 63;
    size_t row = (size_t)blockIdx.x*4 + w;
    int pc = (int)(row / NFFT), y = (int)(row % NFFT);
    int iy = min(max(y-21, 0), 245);
    const float* c0 = cls + (size_t)(2*pc)*NPIX + (size_t)iy*246;
    float2* X = A[w]; float2* Y = B[w];
    for (int j = lane; j < NFFT; j += 64) {
        int ix = min(max(j-21, 0), 245);
        X[j] = make_float2(c0[ix], c0[NPIX+ix]);
    }
    __syncthreads();
    fft288_row<false>(X, Y, lane, tw);
    // unpack two real spectra (row-mirror within this row), store half width
    int chA = (pc >> 3)*16 + (pc & 7)*2;
    float2* sA = S + (size_t)chA * SPLANE + (size_t)y * XW;
    float2* sB = sA + SPLANE;
    for (int x = lane; x < XW; x += 64) {
        float2 Av = make_float2(0.f, 0.f), Bv = make_float2(0.f, 0.f);
        if (x <= 144) {
            int m = (NFFT - x) % NFFT;
            float2 zk = X[x], zm = X[m];
            Av = make_float2(0.5f*(zk.x+zm.x),  0.5f*(zk.y-zm.y));
            Bv = make_float2(0.5f*(zk.y+zm.y), -0.5f*(zk.x-zm.x));
        }
        sA[x] = Av; sB[x] = Bv;
    }
}

// ---------- FUSED: fwd col FFT + pointwise Wiener (analytic P, no mirror) + inv col FFT ----------
__global__ __launch_bounds__(256) void k_fft_cols_filter(float2* __restrict__ S,
        const float2* __restrict__ KfT, const float* __restrict__ kP, const float2* __restrict__ tw) {
    __shared__ float2 Abuf[LDSN];
    __shared__ float2 Bbuf[LDSN];
    int t = threadIdx.x, c = t & 7, w = t >> 3;
    int g = blockIdx.x / 128, ch = blockIdx.x % 128;   // g-major: K columns L2-resident
    int xg = g*8 + c;                                   // 0..151
    int b = ch >> 4;
    float2* sb = S + (size_t)ch * SPLANE + xg;
    float2* X = Abuf; float2* Y = Bbuf;
    for (int r = w; r < NFFT; r += 32) X[lidx(r,c)] = sb[(size_t)r * XW];
    __syncthreads();
    fft288_s9<false>(X, Y, w, c, tw);
    // pointwise Wiener
    {
        const float* p9 = kP + ch*9;                    // block-uniform -> SGPR
        float2 wx = tw[xg];
        const float2* Kcol = KfT + (size_t)b*NFFT2 + (size_t)xg*NFFT;
        for (int y = w; y < NFFT; y += 32) {
            float2 v = X[lidx(y,c)];
            float2 K = Kcol[y];
            float2 wy = tw[y];
            float2 R0 = make_float2(p9[1] + (p9[0]+p9[2])*wx.x, (p9[2]-p9[0])*wx.y);
            float2 R1 = make_float2(p9[4] + (p9[3]+p9[5])*wx.x, (p9[5]-p9[3])*wx.y);
            float2 R2 = make_float2(p9[7] + (p9[6]+p9[8])*wx.x, (p9[8]-p9[6])*wx.y);
            float2 P;
            P.x = R1.x + wy.x*(R0.x+R2.x) - wy.y*(R2.y-R0.y);
            P.y = R1.y + wy.x*(R0.y+R2.y) + wy.y*(R2.x-R0.x);
            float kk = K.x*K.x + K.y*K.y;
            float rcp = 1.0f / (kk + P.x*P.x + P.y*P.y);
            float2 H = make_float2(K.x*rcp, -K.y*rcp);
            Y[lidx(y,c)] = cmul(H, v);
        }
    }
    __syncthreads();
    { float2* tp = X; X = Y; Y = tp; }
    fft288_s9<true>(X, Y, w, c, tw);
    // write back only rows needed by the crop [21,267)
    for (int r = w; r < NFFT; r += 32)
        if (r >= 21 && r < 267) sb[(size_t)r * XW] = X[lidx(r,c)];
}

// ---------- FUSED: repack half spectra + inverse row FFT + crop + 1x1 conv 16->64 ----------
__global__ __launch_bounds__(256) void k_ifft_rows_conv(const float2* __restrict__ S,
        const float* __restrict__ w_exp, const float* __restrict__ b_exp,
        float* __restrict__ out, const float2* __restrict__ tw) {
    __shared__ float2 Abuf[LDSN];
    __shared__ float2 Bbuf[LDSN];
    int t = threadIdx.x, c = t & 7, w = t >> 3;
    int b = blockIdx.x / 246;
    int rseq = blockIdx.x % 246;
    int y = rseq + 21;
    int chA = b*16 + 2*c;
    const float2* sA = S + (size_t)chA * SPLANE + (size_t)y * XW;
    const float2* sB = sA + SPLANE;
    float2* X = Abuf; float2* Y = Bbuf;
    for (int j = w; j < NFFT; j += 32) {
        float2 z;
        if (j <= 144) {
            float2 a = sA[j], bb = sB[j];
            z = make_float2(a.x - bb.y, a.y + bb.x);          // Fa + i*Fb
        } else {
            int m = NFFT - j;
            float2 a = sA[m], bb = sB[m];
            z = make_float2(a.x + bb.y, bb.x - a.y);          // conj(Fa) + i*conj(Fb)
        }
        X[lidx(j,c)] = z;
    }
    __syncthreads();
    fft288_s9<true>(X, Y, w, c, tw);
    if (t < 246) {
        const float sc = 1.0f / 82944.0f;
        float v[16];
        #pragma unroll
        for (int h = 0; h < 8; h++) {
            float2 z = X[lidx(t + 21, h)];
            v[2*h]   = z.x * sc;
            v[2*h+1] = z.y * sc;
        }
        float* ob = out + (size_t)b * 64 * NPIX + (size_t)rseq * 246 + t;
        #pragma unroll
        for (int co = 0; co < 64; co++) {
            float a = b_exp[co];
            #pragma unroll
            for (int ci = 0; ci < 16; ci++) a = fmaf(w_exp[co*16+ci], v[ci], a);
            ob[(size_t)co * NPIX] = a;
        }
    }
}

extern "C" void kernel_launch(void* const* d_in, const int* in_sizes, int n_in,
                              void* d_out, int out_size, void* d_ws, size_t ws_size,
                              hipStream_t stream) {
    const float* x     = (const float*)d_in[0];
    const float* ker   = (const float*)d_in[1];
    const float* w_red = (const float*)d_in[2];
    const float* b_red = (const float*)d_in[3];
    const float* w_g1  = (const float*)d_in[4];
    const float* b_g1  = (const float*)d_in[5];
    const float* w_g2  = (const float*)d_in[6];
    const float* b_g2  = (const float*)d_in[7];
    const float* w_g3  = (const float*)d_in[8];
    const float* b_g3  = (const float*)d_in[9];
    const float* w_g4  = (const float*)d_in[10];
    const float* b_g4  = (const float*)d_in[11];
    const float* w_exp = (const float*)d_in[12];
    const float* b_exp = (const float*)d_in[13];
    float* out = (float*)d_out;

    char* ws = (char*)d_ws;
    size_t off = 0;
    auto alloc = [&](size_t bytes) -> char* {
        char* p = ws + off; off += (bytes + 255) & ~(size_t)255; return p;
    };
    float*  cls    = (float*) alloc(7746048ull * 4);              // (8,16,246,246)
    float2* S      = (float2*)alloc((size_t)128 * SPLANE * 8);    // half spectra (128,288,152)
    float*  hb     = (float*) alloc(7495712ull * 4);              // (8,16,242,242) dedicated
    float2* KfT    = (float2*)alloc((size_t)8 * NFFT2 * 8);       // K spectrum transposed
    float*  pooled = (float*) alloc(1152 * 4);
    float*  kP     = (float*) alloc(1152 * 4);
    float2* tw     = (float2*)alloc(288 * 8);
    // ha aliases S (needs 7,620,608 floats <= 11,206,656 float2 of S; dead before S written)
    float*  ha     = (float*)S;

    k_tw<<<1, 320, 0, stream>>>(tw, pooled);
    k_conv1x1_red<<<473, 256, 0, stream>>>(x, w_red, b_red, cls);
    k_conv3x3<246, true ><<<466, 256, 0, stream>>>(cls, w_g1, b_g1, ha);
    k_conv3x3<244, true ><<<462, 256, 0, stream>>>(ha,  w_g2, b_g2, hb);
    k_conv3x3_pool<<<456, 256, 0, stream>>>(hb, w_g3, b_g3, pooled);
    k_kernelP<<<128, 64, 0, stream>>>(pooled, w_g4, b_g4, kP);

    // KfT = fft2(psf(kernel)^T)
    k_psfKT<<<2592, 256, 0, stream>>>(ker, KfT);
    k_fft_rows<false><<<576, 256, 0, stream>>>(KfT, tw);
    k_fft_cols<false><<<288, 256, 0, stream>>>(KfT, tw);

    // S = per-row-unpacked half spectra of edge-padded cls (packed row FFT)
    k_fft_rows_pad_half<<<4608, 256, 0, stream>>>(cls, S, tw);

    // fwd col FFT + pointwise Wiener + inv col FFT, in LDS (19 col-groups x 128 ch)
    k_fft_cols_filter<<<19*128, 256, 0, stream>>>(S, KfT, kP, tw);

    // repack + inverse row FFT + crop + final 1x1 conv
    k_ifft_rows_conv<<<1968, 256, 0, stream>>>(S, w_exp, b_exp, out, tw);
}

// Round 11
// 338.825 us; speedup vs baseline: 1.1168x; 1.0084x over previous
//
#include <hip/hip_runtime.h>
#include <hip/hip_bf16.h>

// ---------- complex helpers ----------
__device__ inline float2 cadd(float2 a, float2 b){ return make_float2(a.x+b.x, a.y+b.y); }
__device__ inline float2 csub(float2 a, float2 b){ return make_float2(a.x-b.x, a.y-b.y); }
__device__ inline float2 cmul(float2 a, float2 b){
    return make_float2(fmaf(a.x,b.x,-a.y*b.y), fmaf(a.x,b.y,a.y*b.x));
}

#define NPIX 60516      // 246*246
#define NFFT 288
#define NFFT2 82944     // 288*288
#define XW 152          // padded half-spectrum width (valid x: 0..144)
#define SPLANE (NFFT*XW)

// Wave-synchronous "barrier": FFT data exchange never crosses a wave
// (fft288_row: 1 wave per FFT; fft288_s9: half-wave per FFT). CDNA waves are
// lockstep and per-wave LDS ops complete in order, so only a compiler
// ordering fence is needed between stages — zero hardware barriers.
#define WSYNC() do { __builtin_amdgcn_wave_barrier(); asm volatile("" ::: "memory"); } while (0)

// LDS index for the 8-col layout: stride 8 + 1 pad float2 per 4 rows
__device__ inline int lidx(int i, int c){ return i*8 + (i>>2) + c; }
#define LDSN 2376

// ---------- butterflies ----------
template<bool INV>
__device__ inline void bf4(float2 a0, float2 a1, float2 a2, float2 a3,
                           float2& b0, float2& b1, float2& b2, float2& b3) {
    float2 t0=cadd(a0,a2), t1=csub(a0,a2), t2=cadd(a1,a3), t3=csub(a1,a3);
    b0=cadd(t0,t2); b2=csub(t0,t2);
    if (!INV) { b1=make_float2(t1.x+t3.y, t1.y-t3.x); b3=make_float2(t1.x-t3.y, t1.y+t3.x); }
    else      { b1=make_float2(t1.x-t3.y, t1.y+t3.x); b3=make_float2(t1.x+t3.y, t1.y-t3.x); }
}
template<bool INV>
__device__ inline void bf3(float2 a0, float2 a1, float2 a2,
                           float2& b0, float2& b1, float2& b2) {
    const float d = INV ? 0.8660254037844386f : -0.8660254037844386f;
    float2 tt=cadd(a1,a2), u=csub(a1,a2);
    b0=cadd(a0,tt);
    b1=make_float2(a0.x-0.5f*tt.x - d*u.y, a0.y-0.5f*tt.y + d*u.x);
    b2=make_float2(a0.x-0.5f*tt.x + d*u.y, a0.y-0.5f*tt.y - d*u.x);
}

// ---------- 288-pt Stockham core, contiguous layout (one wave per row; wave-sync) ----------
template<bool INV>
__device__ inline void fft288_row(float2*& X, float2*& Y, int lane, const float2* __restrict__ tw) {
    auto TW = [&](int k) { float2 v = tw[k]; if (INV) v.y = -v.y; return v; };
    for (int p = lane; p < 72; p += 64) {
        float2 b0,b1,b2,b3;
        bf4<INV>(X[p], X[p+72], X[p+144], X[p+216], b0,b1,b2,b3);
        Y[4*p]=b0; Y[4*p+1]=cmul(b1,TW(p)); Y[4*p+2]=cmul(b2,TW(2*p)); Y[4*p+3]=cmul(b3,TW(3*p));
    }
    WSYNC(); { float2* t=X; X=Y; Y=t; }
    for (int it = lane; it < 72; it += 64) {
        int p = it>>2, q = it&3, i0 = q+4*p;
        float2 b0,b1,b2,b3;
        bf4<INV>(X[i0], X[i0+72], X[i0+144], X[i0+216], b0,b1,b2,b3);
        int o = q+16*p;
        Y[o]=b0; Y[o+4]=cmul(b1,TW(4*p)); Y[o+8]=cmul(b2,TW(8*p)); Y[o+12]=cmul(b3,TW(12*p));
    }
    WSYNC(); { float2* t=X; X=Y; Y=t; }
    for (int it = lane; it < 144; it += 64) {
        int p = it>>4, q = it&15, i0 = q+16*p;
        float2 a0=X[i0], a1=X[i0+144];
        int o = q+32*p;
        Y[o]=cadd(a0,a1); Y[o+16]=cmul(csub(a0,a1),TW(16*p));
    }
    WSYNC(); { float2* t=X; X=Y; Y=t; }
    for (int it = lane; it < 96; it += 64) {
        int p = it>>5, q = it&31, i0 = q+32*p;
        float2 b0,b1,b2;
        bf3<INV>(X[i0], X[i0+96], X[i0+192], b0,b1,b2);
        int o = q+96*p;
        Y[o]=b0; Y[o+32]=cmul(b1,TW(32*p)); Y[o+64]=cmul(b2,TW(64*p));
    }
    WSYNC(); { float2* t=X; X=Y; Y=t; }
    for (int q = lane; q < 96; q += 64) {
        float2 b0,b1,b2;
        bf3<INV>(X[q], X[q+96], X[q+192], b0,b1,b2);
        Y[q]=b0; Y[q+96]=b1; Y[q+192]=b2;
    }
    WSYNC(); { float2* t=X; X=Y; Y=t; }
}

// ---------- 288-pt Stockham core, lidx layout (HALF-WAVE per FFT: f=t>>5, l=t&31; wave-sync) ----------
template<bool INV>
__device__ inline void fft288_s9(float2*& X, float2*& Y, int w, int c, const float2* __restrict__ tw) {
    auto TW = [&](int k) { float2 v = tw[k]; if (INV) v.y = -v.y; return v; };
    for (int p = w; p < 72; p += 32) {
        float2 b0,b1,b2,b3;
        bf4<INV>(X[lidx(p,c)], X[lidx(p+72,c)], X[lidx(p+144,c)], X[lidx(p+216,c)], b0,b1,b2,b3);
        Y[lidx(4*p,c)]=b0; Y[lidx(4*p+1,c)]=cmul(b1,TW(p));
        Y[lidx(4*p+2,c)]=cmul(b2,TW(2*p)); Y[lidx(4*p+3,c)]=cmul(b3,TW(3*p));
    }
    WSYNC(); { float2* t=X; X=Y; Y=t; }
    for (int it = w; it < 72; it += 32) {
        int p = it>>2, q = it&3, i0 = q+4*p;
        float2 b0,b1,b2,b3;
        bf4<INV>(X[lidx(i0,c)], X[lidx(i0+72,c)], X[lidx(i0+144,c)], X[lidx(i0+216,c)], b0,b1,b2,b3);
        int o = q+16*p;
        Y[lidx(o,c)]=b0; Y[lidx(o+4,c)]=cmul(b1,TW(4*p));
        Y[lidx(o+8,c)]=cmul(b2,TW(8*p)); Y[lidx(o+12,c)]=cmul(b3,TW(12*p));
    }
    WSYNC(); { float2* t=X; X=Y; Y=t; }
    for (int it = w; it < 144; it += 32) {
        int p = it>>4, q = it&15, i0 = q+16*p;
        float2 a0=X[lidx(i0,c)], a1=X[lidx(i0+144,c)];
        int o = q+32*p;
        Y[lidx(o,c)]=cadd(a0,a1); Y[lidx(o+16,c)]=cmul(csub(a0,a1),TW(16*p));
    }
    WSYNC(); { float2* t=X; X=Y; Y=t; }
    for (int it = w; it < 96; it += 32) {
        int p = it>>5, q = it&31, i0 = q+32*p;
        float2 b0,b1,b2;
        bf3<INV>(X[lidx(i0,c)], X[lidx(i0+96,c)], X[lidx(i0+192,c)], b0,b1,b2);
        int o = q+96*p;
        Y[lidx(o,c)]=b0; Y[lidx(o+32,c)]=cmul(b1,TW(32*p)); Y[lidx(o+64,c)]=cmul(b2,TW(64*p));
    }
    WSYNC(); { float2* t=X; X=Y; Y=t; }
    for (int q = w; q < 96; q += 32) {
        float2 b0,b1,b2;
        bf3<INV>(X[lidx(q,c)], X[lidx(q+96,c)], X[lidx(q+192,c)], b0,b1,b2);
        Y[lidx(q,c)]=b0; Y[lidx(q+96,c)]=b1; Y[lidx(q+192,c)]=b2;
    }
    WSYNC(); { float2* t=X; X=Y; Y=t; }
}

// ---------- prep: twiddles + zero pooled ----------
__global__ void k_tw(float2* tw, float* pooled) {
    int t = threadIdx.x;
    if (t < NFFT) {
        double ang = -2.0 * 3.14159265358979323846 * (double)t / (double)NFFT;
        tw[t] = make_float2((float)cos(ang), (float)sin(ang));
    }
    for (int i = t; i < 1152; i += 320) pooled[i] = 0.f;
}

// ---------- 1x1 conv 64->16, 4 px/thread float4 ----------
__global__ __launch_bounds__(256) void k_conv1x1_red(const float* __restrict__ x,
        const float* __restrict__ w, const float* __restrict__ bias, float* __restrict__ out) {
    const int NP4 = NPIX/4;
    int idx = blockIdx.x * 256 + threadIdx.x;
    if (idx >= 8 * NP4) return;
    int b = idx / NP4, p4 = idx % NP4;
    const float4* xb = (const float4*)(x + (size_t)b * 64 * NPIX) + p4;
    float4 acc[16];
    #pragma unroll
    for (int co = 0; co < 16; co++) { float bb = bias[co]; acc[co] = make_float4(bb,bb,bb,bb); }
    for (int ci = 0; ci < 64; ci++) {
        float4 v = xb[(size_t)ci * NP4];
        #pragma unroll
        for (int co = 0; co < 16; co++) {
            float wv = w[co*64+ci];
            acc[co].x = fmaf(wv, v.x, acc[co].x);
            acc[co].y = fmaf(wv, v.y, acc[co].y);
            acc[co].z = fmaf(wv, v.z, acc[co].z);
            acc[co].w = fmaf(wv, v.w, acc[co].w);
        }
    }
    float4* ob = (float4*)(out + (size_t)b * 16 * NPIX) + p4;
    #pragma unroll
    for (int co = 0; co < 16; co++) ob[(size_t)co*NP4] = acc[co];
}

// ---------- 3x3 valid conv 16->16, 4 px/thread, scalar weights ----------
template<int HIN, bool LEAKY>
__global__ __launch_bounds__(256) void k_conv3x3(const float* __restrict__ in,
        const float* __restrict__ w, const float* __restrict__ bias, float* __restrict__ out) {
    const int HOUT = HIN - 2;
    const int GX = (HOUT + 3) / 4;
    int idx = blockIdx.x * 256 + threadIdx.x;
    if (idx >= 8 * HOUT * GX) return;
    int b  = idx / (HOUT * GX);
    int r  = idx % (HOUT * GX);
    int oy = r / GX;
    int ox0 = (r % GX) * 4;

    float acc[16][4];
    #pragma unroll
    for (int co = 0; co < 16; co++) {
        float bb = bias[co];
        #pragma unroll
        for (int px = 0; px < 4; px++) acc[co][px] = bb;
    }
    const float* ib = in + (size_t)b * 16 * HIN * HIN + (size_t)oy * HIN;
    for (int ci = 0; ci < 16; ci++) {
        const float* ic = ib + (size_t)ci * HIN * HIN;
        #pragma unroll
        for (int ky = 0; ky < 3; ky++) {
            float in6[6];
            #pragma unroll
            for (int j = 0; j < 6; j++) {
                int xx = ox0 + j;
                if (HOUT % 4 != 0) { if (xx > HIN - 1) xx = HIN - 1; }
                in6[j] = ic[ky * HIN + xx];
            }
            #pragma unroll
            for (int kx = 0; kx < 3; kx++) {
                #pragma unroll
                for (int co = 0; co < 16; co++) {
                    float wv = w[co*144 + ci*9 + ky*3 + kx];
                    #pragma unroll
                    for (int px = 0; px < 4; px++)
                        acc[co][px] = fmaf(wv, in6[px + kx], acc[co][px]);
                }
            }
        }
    }
    float* ob = out + (size_t)b * 16 * HOUT * HOUT + (size_t)oy * HOUT + ox0;
    #pragma unroll
    for (int co = 0; co < 16; co++) {
        #pragma unroll
        for (int px = 0; px < 4; px++) {
            if (HOUT % 4 == 0 || ox0 + px < HOUT) {
                float v = acc[co][px];
                if (LEAKY) v = (v >= 0.f) ? v : 0.1f * v;
                ob[(size_t)co * HOUT * HOUT + px] = v;
            }
        }
    }
}

// ---------- 3x3 conv (242->240) fused with adaptive pool -> pooled (raw sums) ----------
__global__ __launch_bounds__(256) void k_conv3x3_pool(const float* __restrict__ in,
        const float* __restrict__ w, const float* __restrict__ bias, float* __restrict__ pooled) {
    const int HIN = 242, GX = 60;
    __shared__ float cs[144];
    int t = threadIdx.x;
    int b = blockIdx.x / 57;
    int r = (blockIdx.x % 57) * 256 + t;
    bool valid = r < 14400;
    float partial[16];
    int cell = 0;
    if (valid) {
        int oy = r / GX, ox0 = (r % GX) * 4;
        cell = (oy / 80) * 3 + (ox0 / 80);
        float acc[16][4];
        #pragma unroll
        for (int co = 0; co < 16; co++) {
            float bb = bias[co];
            #pragma unroll
            for (int px = 0; px < 4; px++) acc[co][px] = bb;
        }
        const float* ib = in + (size_t)b * 16 * HIN * HIN + (size_t)oy * HIN;
        for (int ci = 0; ci < 16; ci++) {
            const float* ic = ib + (size_t)ci * HIN * HIN;
            #pragma unroll
            for (int ky = 0; ky < 3; ky++) {
                float in6[6];
                #pragma unroll
                for (int j = 0; j < 6; j++) in6[j] = ic[ky * HIN + ox0 + j];
                #pragma unroll
                for (int kx = 0; kx < 3; kx++) {
                    #pragma unroll
                    for (int co = 0; co < 16; co++) {
                        float wv = w[co*144 + ci*9 + ky*3 + kx];
                        #pragma unroll
                        for (int px = 0; px < 4; px++)
                            acc[co][px] = fmaf(wv, in6[px + kx], acc[co][px]);
                    }
                }
            }
        }
        #pragma unroll
        for (int co = 0; co < 16; co++)
            partial[co] = (acc[co][0] + acc[co][1]) + (acc[co][2] + acc[co][3]);
    }
    if (t < 144) cs[t] = 0.f;
    __syncthreads();
    if (valid) {
        #pragma unroll
        for (int co = 0; co < 16; co++) atomicAdd(&cs[co*9 + cell], partial[co]);
    }
    __syncthreads();
    if (t < 144) atomicAdd(&pooled[b*144 + t], cs[t]);
}

// ---------- kernel_P: 1x1 conv (16->16) + exp + spatial-mean subtraction ----------
__global__ void k_kernelP(const float* __restrict__ pooled, const float* __restrict__ w,
                          const float* __restrict__ bias, float* __restrict__ out) {
    int b = blockIdx.x / 16, co = blockIdx.x % 16;
    __shared__ float vals[9];
    int t = threadIdx.x;
    if (t < 9) {
        float a = 0.f;
        for (int ci = 0; ci < 16; ci++) a += pooled[(b*16+ci)*9 + t] * w[co*16+ci];
        vals[t] = expf(bias[co] + a * (1.f/6400.f));
    }
    __syncthreads();
    if (t < 9) {
        float m = 0.f;
        #pragma unroll
        for (int i = 0; i < 9; i++) m += vals[i];
        m *= (1.f/9.f);
        out[(b*16+co)*9 + t] = vals[t] - m;
    }
}

// ---------- psf builder for K, TRANSPOSED: KfT[b][u][v] = psf[b][v][u] ----------
__global__ __launch_bounds__(256) void k_psfKT(const float* __restrict__ ker, float2* __restrict__ KfT) {
    int idx = blockIdx.x*256 + threadIdx.x;
    if (idx >= 8*NFFT2) return;
    int pos = idx % NFFT2, b = idx / NFFT2;
    int u = pos / NFFT, v = pos % NFFT;
    int ry = (v < 11) ? v+10 : ((v >= 278) ? v-278 : -1);
    int rx = (u < 11) ? u+10 : ((u >= 278) ? u-278 : -1);
    float val = (ry >= 0 && rx >= 0) ? ker[b*441 + ry*21 + rx] : 0.f;
    KfT[idx] = make_float2(val, 0.f);
}

// ---------- plain row FFT (for KfT) — fully wave-local, zero barriers ----------
template<bool INV>
__global__ __launch_bounds__(256) void k_fft_rows(float2* __restrict__ M, const float2* __restrict__ tw) {
    __shared__ float2 A[4][NFFT];
    __shared__ float2 B[4][NFFT];
    int t = threadIdx.x, w = t >> 6, lane = t & 63;
    size_t row = (size_t)blockIdx.x*4 + w;
    float2* X = A[w]; float2* Y = B[w];
    float2* s = M + row*NFFT;
    for (int j = lane; j < NFFT; j += 64) X[j] = s[j];
    WSYNC();
    fft288_row<INV>(X, Y, lane, tw);
    for (int j = lane; j < NFFT; j += 64) s[j] = X[j];
}

// ---------- plain col FFT (for KfT) ----------
template<bool INV>
__global__ __launch_bounds__(256) void k_fft_cols(float2* __restrict__ M, const float2* __restrict__ tw) {
    __shared__ float2 Abuf[LDSN];
    __shared__ float2 Bbuf[LDSN];
    int t = threadIdx.x, c = t & 7, w = t >> 3;
    int f = t >> 5, l = t & 31;          // half-wave FFT ownership for compute
    int ch = blockIdx.x / 36, cg = blockIdx.x % 36;
    float2* base = M + (size_t)ch * NFFT2 + cg*8 + c;
    float2* X = Abuf; float2* Y = Bbuf;
    for (int r = w; r < NFFT; r += 32) X[lidx(r,c)] = base[(size_t)r * NFFT];
    __syncthreads();                     // cross-wave writers into each FFT region
    fft288_s9<INV>(X, Y, l, f, tw);
    __syncthreads();                     // cross-wave readers below
    for (int r = w; r < NFFT; r += 32) base[(size_t)r * NFFT] = X[lidx(r,c)];
}

// ---------- forward row FFT + edge-pad + per-row real unpack — fully wave-local ----------
__global__ __launch_bounds__(256) void k_fft_rows_pad_half(const float* __restrict__ cls,
        float2* __restrict__ S, const float2* __restrict__ tw) {
    __shared__ float2 A[4][NFFT];
    __shared__ float2 B[4][NFFT];
    int t = threadIdx.x, w = t >> 6, lane = t & 63;
    size_t row = (size_t)blockIdx.x*4 + w;
    int pc = (int)(row / NFFT), y = (int)(row % NFFT);
    int iy = min(max(y-21, 0), 245);
    const float* c0 = cls + (size_t)(2*pc)*NPIX + (size_t)iy*246;
    float2* X = A[w]; float2* Y = B[w];
    for (int j = lane; j < NFFT; j += 64) {
        int ix = min(max(j-21, 0), 245);
        X[j] = make_float2(c0[ix], c0[NPIX+ix]);
    }
    WSYNC();
    fft288_row<false>(X, Y, lane, tw);
    // unpack two real spectra (row-mirror within this row), store half width
    int chA = (pc >> 3)*16 + (pc & 7)*2;
    float2* sA = S + (size_t)chA * SPLANE + (size_t)y * XW;
    float2* sB = sA + SPLANE;
    for (int x = lane; x < XW; x += 64) {
        float2 Av = make_float2(0.f, 0.f), Bv = make_float2(0.f, 0.f);
        if (x <= 144) {
            int m = (NFFT - x) % NFFT;
            float2 zk = X[x], zm = X[m];
            Av = make_float2(0.5f*(zk.x+zm.x),  0.5f*(zk.y-zm.y));
            Bv = make_float2(0.5f*(zk.y+zm.y), -0.5f*(zk.x-zm.x));
        }
        sA[x] = Av; sB[x] = Bv;
    }
}

// ---------- FUSED: fwd col FFT + pointwise Wiener (analytic P) + inv col FFT ----------
__global__ __launch_bounds__(256) void k_fft_cols_filter(float2* __restrict__ S,
        const float2* __restrict__ KfT, const float* __restrict__ kP, const float2* __restrict__ tw) {
    __shared__ float2 Abuf[LDSN];
    __shared__ float2 Bbuf[LDSN];
    int t = threadIdx.x, c = t & 7, w = t >> 3;
    int f = t >> 5, l = t & 31;          // half-wave FFT ownership for compute
    int g = blockIdx.x / 128, ch = blockIdx.x % 128;   // g-major: K columns L2-resident
    int b = ch >> 4;
    float2* sb = S + (size_t)ch * SPLANE + g*8;
    float2* X = Abuf; float2* Y = Bbuf;
    for (int r = w; r < NFFT; r += 32) X[lidx(r,c)] = sb[(size_t)r * XW + c];
    __syncthreads();                     // cross-wave writers into each FFT region
    fft288_s9<false>(X, Y, l, f, tw);
    // pointwise Wiener — each half-wave filters its own column f
    {
        const float* p9 = kP + ch*9;     // block-uniform -> SGPR
        int xgf = g*8 + f;
        float2 wx = tw[xgf];
        const float2* Kcol = KfT + (size_t)b*NFFT2 + (size_t)xgf*NFFT;
        for (int y = l; y < NFFT; y += 32) {
            float2 v = X[lidx(y,f)];
            float2 K = Kcol[y];
            float2 wy = tw[y];
            float2 R0 = make_float2(p9[1] + (p9[0]+p9[2])*wx.x, (p9[2]-p9[0])*wx.y);
            float2 R1 = make_float2(p9[4] + (p9[3]+p9[5])*wx.x, (p9[5]-p9[3])*wx.y);
            float2 R2 = make_float2(p9[7] + (p9[6]+p9[8])*wx.x, (p9[8]-p9[6])*wx.y);
            float2 P;
            P.x = R1.x + wy.x*(R0.x+R2.x) - wy.y*(R2.y-R0.y);
            P.y = R1.y + wy.x*(R0.y+R2.y) + wy.y*(R2.x-R0.x);
            float kk = K.x*K.x + K.y*K.y;
            float rcp = 1.0f / (kk + P.x*P.x + P.y*P.y);
            float2 H = make_float2(K.x*rcp, -K.y*rcp);
            Y[lidx(y,f)] = cmul(H, v);
        }
    }
    WSYNC();
    { float2* tp = X; X = Y; Y = tp; }
    fft288_s9<true>(X, Y, l, f, tw);
    __syncthreads();                     // cross-wave readers below
    // write back only rows needed by the crop [21,267)
    for (int r = w; r < NFFT; r += 32)
        if (r >= 21 && r < 267) sb[(size_t)r * XW + c] = X[lidx(r,c)];
}

// ---------- FUSED: repack half spectra + inverse row FFT + crop + 1x1 conv 16->64 ----------
__global__ __launch_bounds__(256) void k_ifft_rows_conv(const float2* __restrict__ S,
        const float* __restrict__ w_exp, const float* __restrict__ b_exp,
        float* __restrict__ out, const float2* __restrict__ tw) {
    __shared__ float2 Abuf[LDSN];
    __shared__ float2 Bbuf[LDSN];
    int t = threadIdx.x;
    int f = t >> 5, l = t & 31;          // half-wave FFT ownership for compute
    int b = blockIdx.x / 246;
    int rseq = blockIdx.x % 246;
    int y = rseq + 21;
    const float2* sbase = S + (size_t)(b*16) * SPLANE + (size_t)y * XW;
    float2* X = Abuf; float2* Y = Bbuf;
    for (int idx = t; idx < 2304; idx += 256) {
        int h = idx & 7, j = idx >> 3;
        const float2* sA = sbase + (size_t)(2*h) * SPLANE;
        const float2* sB = sA + SPLANE;
        float2 z;
        if (j <= 144) {
            float2 a = sA[j], bb = sB[j];
            z = make_float2(a.x - bb.y, a.y + bb.x);          // Fa + i*Fb
        } else {
            int m = NFFT - j;
            float2 a = sA[m], bb = sB[m];
            z = make_float2(a.x + bb.y, bb.x - a.y);          // conj(Fa) + i*conj(Fb)
        }
        X[lidx(j,h)] = z;
    }
    __syncthreads();                     // cross-wave writers into each FFT region
    fft288_s9<true>(X, Y, l, f, tw);
    __syncthreads();                     // conv tail reads all FFT regions
    if (t < 246) {
        const float sc = 1.0f / 82944.0f;
        float v[16];
        #pragma unroll
        for (int h = 0; h < 8; h++) {
            float2 z = X[lidx(t + 21, h)];
            v[2*h]   = z.x * sc;
            v[2*h+1] = z.y * sc;
        }
        float* ob = out + (size_t)b * 64 * NPIX + (size_t)rseq * 246 + t;
        #pragma unroll
        for (int co = 0; co < 64; co++) {
            float a = b_exp[co];
            #pragma unroll
            for (int ci = 0; ci < 16; ci++) a = fmaf(w_exp[co*16+ci], v[ci], a);
            ob[(size_t)co * NPIX] = a;
        }
    }
}

extern "C" void kernel_launch(void* const* d_in, const int* in_sizes, int n_in,
                              void* d_out, int out_size, void* d_ws, size_t ws_size,
                              hipStream_t stream) {
    const float* x     = (const float*)d_in[0];
    const float* ker   = (const float*)d_in[1];
    const float* w_red = (const float*)d_in[2];
    const float* b_red = (const float*)d_in[3];
    const float* w_g1  = (const float*)d_in[4];
    const float* b_g1  = (const float*)d_in[5];
    const float* w_g2  = (const float*)d_in[6];
    const float* b_g2  = (const float*)d_in[7];
    const float* w_g3  = (const float*)d_in[8];
    const float* b_g3  = (const float*)d_in[9];
    const float* w_g4  = (const float*)d_in[10];
    const float* b_g4  = (const float*)d_in[11];
    const float* w_exp = (const float*)d_in[12];
    const float* b_exp = (const float*)d_in[13];
    float* out = (float*)d_out;

    char* ws = (char*)d_ws;
    size_t off = 0;
    auto alloc = [&](size_t bytes) -> char* {
        char* p = ws + off; off += (bytes + 255) & ~(size_t)255; return p;
    };
    float*  cls    = (float*) alloc(7746048ull * 4);              // (8,16,246,246)
    float2* S      = (float2*)alloc((size_t)128 * SPLANE * 8);    // half spectra (128,288,152)
    float*  hb     = (float*) alloc(7495712ull * 4);              // (8,16,242,242) dedicated
    float2* KfT    = (float2*)alloc((size_t)8 * NFFT2 * 8);       // K spectrum transposed
    float*  pooled = (float*) alloc(1152 * 4);
    float*  kP     = (float*) alloc(1152 * 4);
    float2* tw     = (float2*)alloc(288 * 8);
    // ha aliases S (needs 7,620,608 floats <= 11,206,656 float2 of S; dead before S written)
    float*  ha     = (float*)S;

    k_tw<<<1, 320, 0, stream>>>(tw, pooled);
    k_conv1x1_red<<<473, 256, 0, stream>>>(x, w_red, b_red, cls);
    k_conv3x3<246, true ><<<466, 256, 0, stream>>>(cls, w_g1, b_g1, ha);
    k_conv3x3<244, true ><<<462, 256, 0, stream>>>(ha,  w_g2, b_g2, hb);
    k_conv3x3_pool<<<456, 256, 0, stream>>>(hb, w_g3, b_g3, pooled);
    k_kernelP<<<128, 64, 0, stream>>>(pooled, w_g4, b_g4, kP);

    // KfT = fft2(psf(kernel)^T)
    k_psfKT<<<2592, 256, 0, stream>>>(ker, KfT);
    k_fft_rows<false><<<576, 256, 0, stream>>>(KfT, tw);
    k_fft_cols<false><<<288, 256, 0, stream>>>(KfT, tw);

    // S = per-row-unpacked half spectra of edge-padded cls (packed row FFT)
    k_fft_rows_pad_half<<<4608, 256, 0, stream>>>(cls, S, tw);

    // fwd col FFT + pointwise Wiener + inv col FFT, in LDS (19 col-groups x 128 ch)
    k_fft_cols_filter<<<19*128, 256, 0, stream>>>(S, KfT, kP, tw);

    // repack + inverse row FFT + crop + final 1x1 conv
    k_ifft_rows_conv<<<1968, 256, 0, stream>>>(S, w_exp, b_exp, out, tw);
}

// Round 12
// 330.988 us; speedup vs baseline: 1.1432x; 1.0237x over previous
//
#include <hip/hip_runtime.h>
#include <hip/hip_bf16.h>

// ---------- complex helpers ----------
__device__ inline float2 cadd(float2 a, float2 b){ return make_float2(a.x+b.x, a.y+b.y); }
__device__ inline float2 csub(float2 a, float2 b){ return make_float2(a.x-b.x, a.y-b.y); }
__device__ inline float2 cmul(float2 a, float2 b){
    return make_float2(fmaf(a.x,b.x,-a.y*b.y), fmaf(a.x,b.y,a.y*b.x));
}

#define NPIX 60516      // 246*246
#define NFFT 288
#define NFFT2 82944     // 288*288
#define XW 152          // padded half-spectrum width (valid x: 0..144)
#define SPLANE (NFFT*XW)

// Wave-synchronous "barrier": FFT data exchange never crosses a wave
// (fft288_row: 1 wave per FFT; fft288_s9: half-wave per FFT). CDNA waves are
// lockstep and per-wave LDS ops complete in order, so only a compiler
// ordering fence is needed between stages — zero hardware barriers.
#define WSYNC() do { __builtin_amdgcn_wave_barrier(); asm volatile("" ::: "memory"); } while (0)

// LDS index for the 8-col layout: stride 8 + 1 pad float2 per 4 rows
__device__ inline int lidx(int i, int c){ return i*8 + (i>>2) + c; }
#define LDSN 2376

// ---------- butterflies ----------
template<bool INV>
__device__ inline void bf4(float2 a0, float2 a1, float2 a2, float2 a3,
                           float2& b0, float2& b1, float2& b2, float2& b3) {
    float2 t0=cadd(a0,a2), t1=csub(a0,a2), t2=cadd(a1,a3), t3=csub(a1,a3);
    b0=cadd(t0,t2); b2=csub(t0,t2);
    if (!INV) { b1=make_float2(t1.x+t3.y, t1.y-t3.x); b3=make_float2(t1.x-t3.y, t1.y+t3.x); }
    else      { b1=make_float2(t1.x-t3.y, t1.y+t3.x); b3=make_float2(t1.x+t3.y, t1.y-t3.x); }
}
template<bool INV>
__device__ inline void bf3(float2 a0, float2 a1, float2 a2,
                           float2& b0, float2& b1, float2& b2) {
    const float d = INV ? 0.8660254037844386f : -0.8660254037844386f;
    float2 tt=cadd(a1,a2), u=csub(a1,a2);
    b0=cadd(a0,tt);
    b1=make_float2(a0.x-0.5f*tt.x - d*u.y, a0.y-0.5f*tt.y + d*u.x);
    b2=make_float2(a0.x-0.5f*tt.x + d*u.y, a0.y-0.5f*tt.y - d*u.x);
}

// ---------- 288-pt Stockham core, contiguous layout (one wave per row; wave-sync) ----------
template<bool INV>
__device__ inline void fft288_row(float2*& X, float2*& Y, int lane, const float2* __restrict__ tw) {
    auto TW = [&](int k) { float2 v = tw[k]; if (INV) v.y = -v.y; return v; };
    for (int p = lane; p < 72; p += 64) {
        float2 b0,b1,b2,b3;
        bf4<INV>(X[p], X[p+72], X[p+144], X[p+216], b0,b1,b2,b3);
        Y[4*p]=b0; Y[4*p+1]=cmul(b1,TW(p)); Y[4*p+2]=cmul(b2,TW(2*p)); Y[4*p+3]=cmul(b3,TW(3*p));
    }
    WSYNC(); { float2* t=X; X=Y; Y=t; }
    for (int it = lane; it < 72; it += 64) {
        int p = it>>2, q = it&3, i0 = q+4*p;
        float2 b0,b1,b2,b3;
        bf4<INV>(X[i0], X[i0+72], X[i0+144], X[i0+216], b0,b1,b2,b3);
        int o = q+16*p;
        Y[o]=b0; Y[o+4]=cmul(b1,TW(4*p)); Y[o+8]=cmul(b2,TW(8*p)); Y[o+12]=cmul(b3,TW(12*p));
    }
    WSYNC(); { float2* t=X; X=Y; Y=t; }
    for (int it = lane; it < 144; it += 64) {
        int p = it>>4, q = it&15, i0 = q+16*p;
        float2 a0=X[i0], a1=X[i0+144];
        int o = q+32*p;
        Y[o]=cadd(a0,a1); Y[o+16]=cmul(csub(a0,a1),TW(16*p));
    }
    WSYNC(); { float2* t=X; X=Y; Y=t; }
    for (int it = lane; it < 96; it += 64) {
        int p = it>>5, q = it&31, i0 = q+32*p;
        float2 b0,b1,b2;
        bf3<INV>(X[i0], X[i0+96], X[i0+192], b0,b1,b2);
        int o = q+96*p;
        Y[o]=b0; Y[o+32]=cmul(b1,TW(32*p)); Y[o+64]=cmul(b2,TW(64*p));
    }
    WSYNC(); { float2* t=X; X=Y; Y=t; }
    for (int q = lane; q < 96; q += 64) {
        float2 b0,b1,b2;
        bf3<INV>(X[q], X[q+96], X[q+192], b0,b1,b2);
        Y[q]=b0; Y[q+96]=b1; Y[q+192]=b2;
    }
    WSYNC(); { float2* t=X; X=Y; Y=t; }
}

// ---------- 288-pt Stockham core, lidx layout (HALF-WAVE per FFT: f=t>>5, l=t&31; wave-sync) ----------
template<bool INV>
__device__ inline void fft288_s9(float2*& X, float2*& Y, int w, int c, const float2* __restrict__ tw) {
    auto TW = [&](int k) { float2 v = tw[k]; if (INV) v.y = -v.y; return v; };
    for (int p = w; p < 72; p += 32) {
        float2 b0,b1,b2,b3;
        bf4<INV>(X[lidx(p,c)], X[lidx(p+72,c)], X[lidx(p+144,c)], X[lidx(p+216,c)], b0,b1,b2,b3);
        Y[lidx(4*p,c)]=b0; Y[lidx(4*p+1,c)]=cmul(b1,TW(p));
        Y[lidx(4*p+2,c)]=cmul(b2,TW(2*p)); Y[lidx(4*p+3,c)]=cmul(b3,TW(3*p));
    }
    WSYNC(); { float2* t=X; X=Y; Y=t; }
    for (int it = w; it < 72; it += 32) {
        int p = it>>2, q = it&3, i0 = q+4*p;
        float2 b0,b1,b2,b3;
        bf4<INV>(X[lidx(i0,c)], X[lidx(i0+72,c)], X[lidx(i0+144,c)], X[lidx(i0+216,c)], b0,b1,b2,b3);
        int o = q+16*p;
        Y[lidx(o,c)]=b0; Y[lidx(o+4,c)]=cmul(b1,TW(4*p));
        Y[lidx(o+8,c)]=cmul(b2,TW(8*p)); Y[lidx(o+12,c)]=cmul(b3,TW(12*p));
    }
    WSYNC(); { float2* t=X; X=Y; Y=t; }
    for (int it = w; it < 144; it += 32) {
        int p = it>>4, q = it&15, i0 = q+16*p;
        float2 a0=X[lidx(i0,c)], a1=X[lidx(i0+144,c)];
        int o = q+32*p;
        Y[lidx(o,c)]=cadd(a0,a1); Y[lidx(o+16,c)]=cmul(csub(a0,a1),TW(16*p));
    }
    WSYNC(); { float2* t=X; X=Y; Y=t; }
    for (int it = w; it < 96; it += 32) {
        int p = it>>5, q = it&31, i0 = q+32*p;
        float2 b0,b1,b2;
        bf3<INV>(X[lidx(i0,c)], X[lidx(i0+96,c)], X[lidx(i0+192,c)], b0,b1,b2);
        int o = q+96*p;
        Y[lidx(o,c)]=b0; Y[lidx(o+32,c)]=cmul(b1,TW(32*p)); Y[lidx(o+64,c)]=cmul(b2,TW(64*p));
    }
    WSYNC(); { float2* t=X; X=Y; Y=t; }
    for (int q = w; q < 96; q += 32) {
        float2 b0,b1,b2;
        bf3<INV>(X[lidx(q,c)], X[lidx(q+96,c)], X[lidx(q+192,c)], b0,b1,b2);
        Y[lidx(q,c)]=b0; Y[lidx(q+96,c)]=b1; Y[lidx(q+192,c)]=b2;
    }
    WSYNC(); { float2* t=X; X=Y; Y=t; }
}

// ---------- prep: twiddles + zero pooled ----------
__global__ void k_tw(float2* tw, float* pooled) {
    int t = threadIdx.x;
    if (t < NFFT) {
        double ang = -2.0 * 3.14159265358979323846 * (double)t / (double)NFFT;
        tw[t] = make_float2((float)cos(ang), (float)sin(ang));
    }
    for (int i = t; i < 1152; i += 320) pooled[i] = 0.f;
}

// ---------- 1x1 conv 64->16, 4 px/thread float4 ----------
__global__ __launch_bounds__(256) void k_conv1x1_red(const float* __restrict__ x,
        const float* __restrict__ w, const float* __restrict__ bias, float* __restrict__ out) {
    const int NP4 = NPIX/4;
    int idx = blockIdx.x * 256 + threadIdx.x;
    if (idx >= 8 * NP4) return;
    int b = idx / NP4, p4 = idx % NP4;
    const float4* xb = (const float4*)(x + (size_t)b * 64 * NPIX) + p4;
    float4 acc[16];
    #pragma unroll
    for (int co = 0; co < 16; co++) { float bb = bias[co]; acc[co] = make_float4(bb,bb,bb,bb); }
    for (int ci = 0; ci < 64; ci++) {
        float4 v = xb[(size_t)ci * NP4];
        #pragma unroll
        for (int co = 0; co < 16; co++) {
            float wv = w[co*64+ci];
            acc[co].x = fmaf(wv, v.x, acc[co].x);
            acc[co].y = fmaf(wv, v.y, acc[co].y);
            acc[co].z = fmaf(wv, v.z, acc[co].z);
            acc[co].w = fmaf(wv, v.w, acc[co].w);
        }
    }
    float4* ob = (float4*)(out + (size_t)b * 16 * NPIX) + p4;
    #pragma unroll
    for (int co = 0; co < 16; co++) ob[(size_t)co*NP4] = acc[co];
}

// ---------- 3x3 valid conv 16->16, 4 px/thread, scalar weights ----------
template<int HIN, bool LEAKY>
__global__ __launch_bounds__(256) void k_conv3x3(const float* __restrict__ in,
        const float* __restrict__ w, const float* __restrict__ bias, float* __restrict__ out) {
    const int HOUT = HIN - 2;
    const int GX = (HOUT + 3) / 4;
    int idx = blockIdx.x * 256 + threadIdx.x;
    if (idx >= 8 * HOUT * GX) return;
    int b  = idx / (HOUT * GX);
    int r  = idx % (HOUT * GX);
    int oy = r / GX;
    int ox0 = (r % GX) * 4;

    float acc[16][4];
    #pragma unroll
    for (int co = 0; co < 16; co++) {
        float bb = bias[co];
        #pragma unroll
        for (int px = 0; px < 4; px++) acc[co][px] = bb;
    }
    const float* ib = in + (size_t)b * 16 * HIN * HIN + (size_t)oy * HIN;
    for (int ci = 0; ci < 16; ci++) {
        const float* ic = ib + (size_t)ci * HIN * HIN;
        #pragma unroll
        for (int ky = 0; ky < 3; ky++) {
            float in6[6];
            #pragma unroll
            for (int j = 0; j < 6; j++) {
                int xx = ox0 + j;
                if (HOUT % 4 != 0) { if (xx > HIN - 1) xx = HIN - 1; }
                in6[j] = ic[ky * HIN + xx];
            }
            #pragma unroll
            for (int kx = 0; kx < 3; kx++) {
                #pragma unroll
                for (int co = 0; co < 16; co++) {
                    float wv = w[co*144 + ci*9 + ky*3 + kx];
                    #pragma unroll
                    for (int px = 0; px < 4; px++)
                        acc[co][px] = fmaf(wv, in6[px + kx], acc[co][px]);
                }
            }
        }
    }
    float* ob = out + (size_t)b * 16 * HOUT * HOUT + (size_t)oy * HOUT + ox0;
    #pragma unroll
    for (int co = 0; co < 16; co++) {
        #pragma unroll
        for (int px = 0; px < 4; px++) {
            if (HOUT % 4 == 0 || ox0 + px < HOUT) {
                float v = acc[co][px];
                if (LEAKY) v = (v >= 0.f) ? v : 0.1f * v;
                ob[(size_t)co * HOUT * HOUT + px] = v;
            }
        }
    }
}

// ---------- 3x3 conv (242->240) fused with adaptive pool -> pooled (raw sums) ----------
__global__ __launch_bounds__(256) void k_conv3x3_pool(const float* __restrict__ in,
        const float* __restrict__ w, const float* __restrict__ bias, float* __restrict__ pooled) {
    const int HIN = 242, GX = 60;
    __shared__ float cs[144];
    int t = threadIdx.x;
    int b = blockIdx.x / 57;
    int r = (blockIdx.x % 57) * 256 + t;
    bool valid = r < 14400;
    float partial[16];
    int cell = 0;
    if (valid) {
        int oy = r / GX, ox0 = (r % GX) * 4;
        cell = (oy / 80) * 3 + (ox0 / 80);
        float acc[16][4];
        #pragma unroll
        for (int co = 0; co < 16; co++) {
            float bb = bias[co];
            #pragma unroll
            for (int px = 0; px < 4; px++) acc[co][px] = bb;
        }
        const float* ib = in + (size_t)b * 16 * HIN * HIN + (size_t)oy * HIN;
        for (int ci = 0; ci < 16; ci++) {
            const float* ic = ib + (size_t)ci * HIN * HIN;
            #pragma unroll
            for (int ky = 0; ky < 3; ky++) {
                float in6[6];
                #pragma unroll
                for (int j = 0; j < 6; j++) in6[j] = ic[ky * HIN + ox0 + j];
                #pragma unroll
                for (int kx = 0; kx < 3; kx++) {
                    #pragma unroll
                    for (int co = 0; co < 16; co++) {
                        float wv = w[co*144 + ci*9 + ky*3 + kx];
                        #pragma unroll
                        for (int px = 0; px < 4; px++)
                            acc[co][px] = fmaf(wv, in6[px + kx], acc[co][px]);
                    }
                }
            }
        }
        #pragma unroll
        for (int co = 0; co < 16; co++)
            partial[co] = (acc[co][0] + acc[co][1]) + (acc[co][2] + acc[co][3]);
    }
    if (t < 144) cs[t] = 0.f;
    __syncthreads();
    if (valid) {
        #pragma unroll
        for (int co = 0; co < 16; co++) atomicAdd(&cs[co*9 + cell], partial[co]);
    }
    __syncthreads();
    if (t < 144) atomicAdd(&pooled[b*144 + t], cs[t]);
}

// ---------- kernel_P: 1x1 conv (16->16) + exp + spatial-mean subtraction ----------
__global__ void k_kernelP(const float* __restrict__ pooled, const float* __restrict__ w,
                          const float* __restrict__ bias, float* __restrict__ out) {
    int b = blockIdx.x / 16, co = blockIdx.x % 16;
    __shared__ float vals[9];
    int t = threadIdx.x;
    if (t < 9) {
        float a = 0.f;
        for (int ci = 0; ci < 16; ci++) a += pooled[(b*16+ci)*9 + t] * w[co*16+ci];
        vals[t] = expf(bias[co] + a * (1.f/6400.f));
    }
    __syncthreads();
    if (t < 9) {
        float m = 0.f;
        #pragma unroll
        for (int i = 0; i < 9; i++) m += vals[i];
        m *= (1.f/9.f);
        out[(b*16+co)*9 + t] = vals[t] - m;
    }
}

// ---------- psf builder for K, TRANSPOSED: KfT[b][u][v] = psf[b][v][u] ----------
__global__ __launch_bounds__(256) void k_psfKT(const float* __restrict__ ker, float2* __restrict__ KfT) {
    int idx = blockIdx.x*256 + threadIdx.x;
    if (idx >= 8*NFFT2) return;
    int pos = idx % NFFT2, b = idx / NFFT2;
    int u = pos / NFFT, v = pos % NFFT;
    int ry = (v < 11) ? v+10 : ((v >= 278) ? v-278 : -1);
    int rx = (u < 11) ? u+10 : ((u >= 278) ? u-278 : -1);
    float val = (ry >= 0 && rx >= 0) ? ker[b*441 + ry*21 + rx] : 0.f;
    KfT[idx] = make_float2(val, 0.f);
}

// ---------- plain row FFT (for KfT) — fully wave-local, zero barriers ----------
template<bool INV>
__global__ __launch_bounds__(256) void k_fft_rows(float2* __restrict__ M, const float2* __restrict__ tw) {
    __shared__ float2 A[4][NFFT];
    __shared__ float2 B[4][NFFT];
    int t = threadIdx.x, w = t >> 6, lane = t & 63;
    size_t row = (size_t)blockIdx.x*4 + w;
    float2* X = A[w]; float2* Y = B[w];
    float2* s = M + row*NFFT;
    for (int j = lane; j < NFFT; j += 64) X[j] = s[j];
    WSYNC();
    fft288_row<INV>(X, Y, lane, tw);
    for (int j = lane; j < NFFT; j += 64) s[j] = X[j];
}

// ---------- plain col FFT (for KfT) ----------
template<bool INV>
__global__ __launch_bounds__(256) void k_fft_cols(float2* __restrict__ M, const float2* __restrict__ tw) {
    __shared__ float2 Abuf[LDSN];
    __shared__ float2 Bbuf[LDSN];
    int t = threadIdx.x, c = t & 7, w = t >> 3;
    int f = t >> 5, l = t & 31;          // half-wave FFT ownership for compute
    int ch = blockIdx.x / 36, cg = blockIdx.x % 36;
    float2* base = M + (size_t)ch * NFFT2 + cg*8 + c;
    float2* X = Abuf; float2* Y = Bbuf;
    for (int r = w; r < NFFT; r += 32) X[lidx(r,c)] = base[(size_t)r * NFFT];
    __syncthreads();                     // cross-wave writers into each FFT region
    fft288_s9<INV>(X, Y, l, f, tw);
    __syncthreads();                     // cross-wave readers below
    for (int r = w; r < NFFT; r += 32) base[(size_t)r * NFFT] = X[lidx(r,c)];
}

// ---------- forward row FFT + edge-pad + per-row real unpack — fully wave-local ----------
__global__ __launch_bounds__(256) void k_fft_rows_pad_half(const float* __restrict__ cls,
        float2* __restrict__ S, const float2* __restrict__ tw) {
    __shared__ float2 A[4][NFFT];
    __shared__ float2 B[4][NFFT];
    int t = threadIdx.x, w = t >> 6, lane = t & 63;
    size_t row = (size_t)blockIdx.x*4 + w;
    int pc = (int)(row / NFFT), y = (int)(row % NFFT);
    int iy = min(max(y-21, 0), 245);
    const float* c0 = cls + (size_t)(2*pc)*NPIX + (size_t)iy*246;
    float2* X = A[w]; float2* Y = B[w];
    for (int j = lane; j < NFFT; j += 64) {
        int ix = min(max(j-21, 0), 245);
        X[j] = make_float2(c0[ix], c0[NPIX+ix]);
    }
    WSYNC();
    fft288_row<false>(X, Y, lane, tw);
    // unpack two real spectra (row-mirror within this row), store half width
    int chA = (pc >> 3)*16 + (pc & 7)*2;
    float2* sA = S + (size_t)chA * SPLANE + (size_t)y * XW;
    float2* sB = sA + SPLANE;
    for (int x = lane; x < XW; x += 64) {
        float2 Av = make_float2(0.f, 0.f), Bv = make_float2(0.f, 0.f);
        if (x <= 144) {
            int m = (NFFT - x) % NFFT;
            float2 zk = X[x], zm = X[m];
            Av = make_float2(0.5f*(zk.x+zm.x),  0.5f*(zk.y-zm.y));
            Bv = make_float2(0.5f*(zk.y+zm.y), -0.5f*(zk.x-zm.x));
        }
        sA[x] = Av; sB[x] = Bv;
    }
}

// ---------- FUSED: fwd col FFT + pointwise Wiener (analytic P) + inv col FFT ----------
__global__ __launch_bounds__(256) void k_fft_cols_filter(float2* __restrict__ S,
        const float2* __restrict__ KfT, const float* __restrict__ kP, const float2* __restrict__ tw) {
    __shared__ float2 Abuf[LDSN];
    __shared__ float2 Bbuf[LDSN];
    int t = threadIdx.x, c = t & 7, w = t >> 3;
    int f = t >> 5, l = t & 31;          // half-wave FFT ownership for compute
    int g = blockIdx.x / 128, ch = blockIdx.x % 128;   // g-major: K columns L2-resident
    int b = ch >> 4;
    float2* sb = S + (size_t)ch * SPLANE + g*8;
    float2* X = Abuf; float2* Y = Bbuf;
    for (int r = w; r < NFFT; r += 32) X[lidx(r,c)] = sb[(size_t)r * XW + c];
    __syncthreads();                     // cross-wave writers into each FFT region
    fft288_s9<false>(X, Y, l, f, tw);
    // pointwise Wiener — each half-wave filters its own column f
    {
        const float* p9 = kP + ch*9;     // block-uniform -> SGPR
        int xgf = g*8 + f;
        float2 wx = tw[xgf];
        const float2* Kcol = KfT + (size_t)b*NFFT2 + (size_t)xgf*NFFT;
        for (int y = l; y < NFFT; y += 32) {
            float2 v = X[lidx(y,f)];
            float2 K = Kcol[y];
            float2 wy = tw[y];
            float2 R0 = make_float2(p9[1] + (p9[0]+p9[2])*wx.x, (p9[2]-p9[0])*wx.y);
            float2 R1 = make_float2(p9[4] + (p9[3]+p9[5])*wx.x, (p9[5]-p9[3])*wx.y);
            float2 R2 = make_float2(p9[7] + (p9[6]+p9[8])*wx.x, (p9[8]-p9[6])*wx.y);
            float2 P;
            P.x = R1.x + wy.x*(R0.x+R2.x) - wy.y*(R2.y-R0.y);
            P.y = R1.y + wy.x*(R0.y+R2.y) + wy.y*(R2.x-R0.x);
            float kk = K.x*K.x + K.y*K.y;
            float rcp = 1.0f / (kk + P.x*P.x + P.y*P.y);
            float2 H = make_float2(K.x*rcp, -K.y*rcp);
            Y[lidx(y,f)] = cmul(H, v);
        }
    }
    WSYNC();
    { float2* tp = X; X = Y; Y = tp; }
    fft288_s9<true>(X, Y, l, f, tw);
    __syncthreads();                     // cross-wave readers below
    // write back only rows needed by the crop [21,267)
    for (int r = w; r < NFFT; r += 32)
        if (r >= 21 && r < 267) sb[(size_t)r * XW + c] = X[lidx(r,c)];
}

// ---------- FUSED: repack half spectra + inverse row FFT + crop + 1x1 conv 16->64 ----------
__global__ __launch_bounds__(256) void k_ifft_rows_conv(const float2* __restrict__ S,
        const float* __restrict__ w_exp, const float* __restrict__ b_exp,
        float* __restrict__ out, const float2* __restrict__ tw) {
    __shared__ float2 Abuf[LDSN];
    __shared__ float2 Bbuf[LDSN];
    int t = threadIdx.x;
    int f = t >> 5, l = t & 31;          // half-wave FFT ownership for compute
    int b = blockIdx.x / 246;
    int rseq = blockIdx.x % 246;
    int y = rseq + 21;
    const float2* sbase = S + (size_t)(b*16) * SPLANE + (size_t)y * XW;
    float2* X = Abuf; float2* Y = Bbuf;
    // ROUND-11 DELTA: gather with j (position) as the FAST index so each wave
    // reads 64 consecutive float2 from ONE plane (512B coalesced bursts),
    // instead of straddling 8 planes per load instruction.
    for (int idx = t; idx < 2304; idx += 256) {
        int h = idx / 288, j = idx % 288;
        const float2* sA = sbase + (size_t)(2*h) * SPLANE;
        const float2* sB = sA + SPLANE;
        float2 z;
        if (j <= 144) {
            float2 a = sA[j], bb = sB[j];
            z = make_float2(a.x - bb.y, a.y + bb.x);          // Fa + i*Fb
        } else {
            int m = NFFT - j;
            float2 a = sA[m], bb = sB[m];
            z = make_float2(a.x + bb.y, bb.x - a.y);          // conj(Fa) + i*conj(Fb)
        }
        X[lidx(j,h)] = z;
    }
    __syncthreads();                     // cross-wave writers into each FFT region
    fft288_s9<true>(X, Y, l, f, tw);
    __syncthreads();                     // conv tail reads all FFT regions
    if (t < 246) {
        const float sc = 1.0f / 82944.0f;
        float v[16];
        #pragma unroll
        for (int h = 0; h < 8; h++) {
            float2 z = X[lidx(t + 21, h)];
            v[2*h]   = z.x * sc;
            v[2*h+1] = z.y * sc;
        }
        float* ob = out + (size_t)b * 64 * NPIX + (size_t)rseq * 246 + t;
        #pragma unroll
        for (int co = 0; co < 64; co++) {
            float a = b_exp[co];
            #pragma unroll
            for (int ci = 0; ci < 16; ci++) a = fmaf(w_exp[co*16+ci], v[ci], a);
            ob[(size_t)co * NPIX] = a;
        }
    }
}

extern "C" void kernel_launch(void* const* d_in, const int* in_sizes, int n_in,
                              void* d_out, int out_size, void* d_ws, size_t ws_size,
                              hipStream_t stream) {
    const float* x     = (const float*)d_in[0];
    const float* ker   = (const float*)d_in[1];
    const float* w_red = (const float*)d_in[2];
    const float* b_red = (const float*)d_in[3];
    const float* w_g1  = (const float*)d_in[4];
    const float* b_g1  = (const float*)d_in[5];
    const float* w_g2  = (const float*)d_in[6];
    const float* b_g2  = (const float*)d_in[7];
    const float* w_g3  = (const float*)d_in[8];
    const float* b_g3  = (const float*)d_in[9];
    const float* w_g4  = (const float*)d_in[10];
    const float* b_g4  = (const float*)d_in[11];
    const float* w_exp = (const float*)d_in[12];
    const float* b_exp = (const float*)d_in[13];
    float* out = (float*)d_out;

    char* ws = (char*)d_ws;
    size_t off = 0;
    auto alloc = [&](size_t bytes) -> char* {
        char* p = ws + off; off += (bytes + 255) & ~(size_t)255; return p;
    };
    float*  cls    = (float*) alloc(7746048ull * 4);              // (8,16,246,246)
    float2* S      = (float2*)alloc((size_t)128 * SPLANE * 8);    // half spectra (128,288,152)
    float*  hb     = (float*) alloc(7495712ull * 4);              // (8,16,242,242) dedicated
    float2* KfT    = (float2*)alloc((size_t)8 * NFFT2 * 8);       // K spectrum transposed
    float*  pooled = (float*) alloc(1152 * 4);
    float*  kP     = (float*) alloc(1152 * 4);
    float2* tw     = (float2*)alloc(288 * 8);
    // ha aliases S (needs 7,620,608 floats <= 11,206,656 float2 of S; dead before S written)
    float*  ha     = (float*)S;

    k_tw<<<1, 320, 0, stream>>>(tw, pooled);
    k_conv1x1_red<<<473, 256, 0, stream>>>(x, w_red, b_red, cls);
    k_conv3x3<246, true ><<<466, 256, 0, stream>>>(cls, w_g1, b_g1, ha);
    k_conv3x3<244, true ><<<462, 256, 0, stream>>>(ha,  w_g2, b_g2, hb);
    k_conv3x3_pool<<<456, 256, 0, stream>>>(hb, w_g3, b_g3, pooled);
    k_kernelP<<<128, 64, 0, stream>>>(pooled, w_g4, b_g4, kP);

    // KfT = fft2(psf(kernel)^T)
    k_psfKT<<<2592, 256, 0, stream>>>(ker, KfT);
    k_fft_rows<false><<<576, 256, 0, stream>>>(KfT, tw);
    k_fft_cols<false><<<288, 256, 0, stream>>>(KfT, tw);

    // S = per-row-unpacked half spectra of edge-padded cls (packed row FFT)
    k_fft_rows_pad_half<<<4608, 256, 0, stream>>>(cls, S, tw);

    // fwd col FFT + pointwise Wiener + inv col FFT, in LDS (19 col-groups x 128 ch)
    k_fft_cols_filter<<<19*128, 256, 0, stream>>>(S, KfT, kP, tw);

    // repack + inverse row FFT + crop + final 1x1 conv
    k_ifft_rows_conv<<<1968, 256, 0, stream>>>(S, w_exp, b_exp, out, tw);
}